// Round 2
// baseline (540.637 us; speedup 1.0000x reference)
//
#include <hip/hip_runtime.h>
#include <hip/hip_fp16.h>

#define NROWS 262144
#define HIDN 50
#define KK 10
#define TDIM 8
#define BB 3.0f
#define H2N 26  // half2 words per thread h-row (25 used + 1 pad); stride 26 -> 6 blocks/CU

// zero the logdet accumulator slot (d_out is poisoned 0xAA before every timed launch)
__global__ void nsf_zero(float* __restrict__ p) {
    if (threadIdx.x == 0) *p = 0.0f;
}

__device__ __forceinline__ float fast_tanh(float a) {
    float e = __expf(2.0f * a);
    return 1.0f - __fdividef(2.0f, e + 1.0f);
}

__global__ __launch_bounds__(256, 6) void nsf_main(
    const float* __restrict__ x,
    const float* __restrict__ w0, const float* __restrict__ b0,
    const float* __restrict__ w1, const float* __restrict__ b1,
    const float* __restrict__ ww, const float* __restrict__ bw,
    const float* __restrict__ wh, const float* __restrict__ bh,
    const float* __restrict__ wd, const float* __restrict__ bd,
    float* __restrict__ out, float* __restrict__ ldsum_out)
{
    __shared__ __half2 hbuf[256 * H2N];
    __shared__ float red[4];

    const int tid = threadIdx.x;
    const int r = blockIdx.x * 256 + tid;

    const float4* xv = (const float4*)x;
    const float4 xv0 = xv[r * 4 + 0];
    const float4 xv1 = xv[r * 4 + 1];

    // passthrough of the 8 scale dims
    float4* ov = (float4*)out;
    ov[r * 4 + 0] = xv0;
    ov[r * 4 + 1] = xv1;

    float acc[HIDN];
    __half2* hrow = &hbuf[tid * H2N];

    // ---- phase 1: h1 = tanh(zd @ w0 + b0) ----
    #pragma unroll
    for (int j = 0; j < HIDN; ++j) acc[j] = b0[j];
    {
        const float z0[8] = {xv0.x, xv0.y, xv0.z, xv0.w, xv1.x, xv1.y, xv1.z, xv1.w};
        #pragma unroll
        for (int k = 0; k < 8; ++k) {
            const float zk = z0[k];
            #pragma unroll
            for (int j = 0; j < HIDN; ++j)
                acc[j] = fmaf(zk, w0[k * HIDN + j], acc[j]);
        }
    }
    #pragma unroll
    for (int j = 0; j < 25; ++j)
        hrow[j] = __floats2half2_rn(fast_tanh(acc[2 * j]), fast_tanh(acc[2 * j + 1]));

    // ---- phase 2: h2 = tanh(h1 @ w1 + b1) ----
    #pragma unroll
    for (int j = 0; j < HIDN; ++j) acc[j] = b1[j];
    #pragma unroll 1
    for (int kb = 0; kb < 12; ++kb) {
        const __half2 p0 = hrow[2 * kb];
        const __half2 p1 = hrow[2 * kb + 1];
        const float h0 = __low2float(p0), h1v = __high2float(p0);
        const float h2v = __low2float(p1), h3v = __high2float(p1);
        const float* wr = w1 + (4 * kb) * HIDN;
        #pragma unroll
        for (int j = 0; j < HIDN; ++j) acc[j] = fmaf(h0, wr[j], acc[j]);
        #pragma unroll
        for (int j = 0; j < HIDN; ++j) acc[j] = fmaf(h1v, wr[HIDN + j], acc[j]);
        #pragma unroll
        for (int j = 0; j < HIDN; ++j) acc[j] = fmaf(h2v, wr[2 * HIDN + j], acc[j]);
        #pragma unroll
        for (int j = 0; j < HIDN; ++j) acc[j] = fmaf(h3v, wr[3 * HIDN + j], acc[j]);
    }
    {   // tail k = 48, 49
        const __half2 p0 = hrow[24];
        const float h0 = __low2float(p0), h1v = __high2float(p0);
        const float* wr = w1 + 48 * HIDN;
        #pragma unroll
        for (int j = 0; j < HIDN; ++j) acc[j] = fmaf(h0, wr[j], acc[j]);
        #pragma unroll
        for (int j = 0; j < HIDN; ++j) acc[j] = fmaf(h1v, wr[HIDN + j], acc[j]);
    }
    #pragma unroll
    for (int j = 0; j < 25; ++j)
        hrow[j] = __floats2half2_rn(fast_tanh(acc[2 * j]), fast_tanh(acc[2 * j + 1]));

    // u values loaded late to reduce peak VGPR pressure during phases 1-2
    const float4 xu0 = xv[r * 4 + 2];
    const float4 xu1 = xv[r * 4 + 3];

    // ---- phase 3: per transformed dim (fully unrolled d; rolled k) ----
    float ldacc = 0.0f;
    float4 zlo, zhi;
    #pragma unroll
    for (int d = 0; d < TDIM; ++d) {
        float aw[KK], ah[KK], ad[KK - 1];
        #pragma unroll
        for (int i = 0; i < KK; ++i)     aw[i] = bw[d * KK + i];
        #pragma unroll
        for (int i = 0; i < KK; ++i)     ah[i] = bh[d * KK + i];
        #pragma unroll
        for (int i = 0; i < KK - 1; ++i) ad[i] = bd[d * (KK - 1) + i];

        #pragma unroll 1
        for (int kb = 0; kb < 12; ++kb) {
            const __half2 p0 = hrow[2 * kb];
            const __half2 p1 = hrow[2 * kb + 1];
            const float hv[4] = {__low2float(p0), __high2float(p0),
                                 __low2float(p1), __high2float(p1)};
            #pragma unroll
            for (int s = 0; s < 4; ++s) {
                const int k = 4 * kb + s;
                const float hk = hv[s];
                const float* wwr = ww + k * (TDIM * KK) + d * KK;
                const float* whr = wh + k * (TDIM * KK) + d * KK;
                const float* wdr = wd + k * (TDIM * (KK - 1)) + d * (KK - 1);
                #pragma unroll
                for (int i = 0; i < KK; ++i)     aw[i] = fmaf(hk, wwr[i], aw[i]);
                #pragma unroll
                for (int i = 0; i < KK; ++i)     ah[i] = fmaf(hk, whr[i], ah[i]);
                #pragma unroll
                for (int i = 0; i < KK - 1; ++i) ad[i] = fmaf(hk, wdr[i], ad[i]);
            }
        }
        {   // tail k = 48, 49
            const __half2 p0 = hrow[24];
            const float hv[2] = {__low2float(p0), __high2float(p0)};
            #pragma unroll
            for (int s = 0; s < 2; ++s) {
                const int k = 48 + s;
                const float hk = hv[s];
                const float* wwr = ww + k * (TDIM * KK) + d * KK;
                const float* whr = wh + k * (TDIM * KK) + d * KK;
                const float* wdr = wd + k * (TDIM * (KK - 1)) + d * (KK - 1);
                #pragma unroll
                for (int i = 0; i < KK; ++i)     aw[i] = fmaf(hk, wwr[i], aw[i]);
                #pragma unroll
                for (int i = 0; i < KK; ++i)     ah[i] = fmaf(hk, whr[i], ah[i]);
                #pragma unroll
                for (int i = 0; i < KK - 1; ++i) ad[i] = fmaf(hk, wdr[i], ad[i]);
            }
        }

        // softmax over K for widths (logits = 6*aw)
        float mw = aw[0];
        #pragma unroll
        for (int i = 1; i < KK; ++i) mw = fmaxf(mw, aw[i]);
        float sw = 0.0f;
        #pragma unroll
        for (int i = 0; i < KK; ++i) { aw[i] = __expf(6.0f * (aw[i] - mw)); sw += aw[i]; }
        const float invw = __fdividef(1.0f, sw);

        // softmax over K for heights
        float mh = ah[0];
        #pragma unroll
        for (int i = 1; i < KK; ++i) mh = fmaxf(mh, ah[i]);
        float sh = 0.0f;
        #pragma unroll
        for (int i = 0; i < KK; ++i) { ah[i] = __expf(6.0f * (ah[i] - mh)); sh += ah[i]; }
        const float invh = __fdividef(1.0f, sh);

        // softplus derivatives
        float sp[KK - 1];
        #pragma unroll
        for (int i = 0; i < KK - 1; ++i) {
            const float v = ad[i];
            sp[i] = fmaxf(v, 0.0f) + __logf(1.0f + __expf(-fabsf(v)));
        }

        // u for this dim (d is compile-time constant here)
        const float4 vsel = (d < 4) ? xu0 : xu1;
        const int dd = d & 3;
        const float ud = (dd == 0) ? vsel.x : (dd == 1) ? vsel.y : (dd == 2) ? vsel.z : vsel.w;
        const float uc = fminf(fmaxf(ud, -BB), BB);
        const bool inside = (ud > -BB) && (ud < BB);

        // streaming bin search + parameter select
        float cw = 0.0f, ch = 0.0f;
        float xprev = -BB, yprev = -BB, dprev = 1.0f;
        float xk = -BB, yk = -BB, wk = 1.0f, hk2 = 1.0f, dk = 1.0f, dk1 = 1.0f;
        #pragma unroll
        for (int i = 0; i < KK; ++i) {
            cw += aw[i] * invw;
            ch += ah[i] * invh;
            const float xnext = fmaf(6.0f, cw, -BB);
            const float ynext = fmaf(6.0f, ch, -BB);
            const float dnext = (i == KK - 1) ? 1.0f : sp[i];
            const bool c = (i == 0) || (uc >= xprev);
            if (c) { xk = xprev; yk = yprev; wk = xnext - xprev; hk2 = ynext - yprev; dk = dprev; dk1 = dnext; }
            xprev = xnext; yprev = ynext; dprev = dnext;
        }

        // rational-quadratic spline
        const float sk = __fdividef(hk2, wk);
        const float xi = __fdividef(uc - xk, wk);
        const float om = 1.0f - xi;
        const float denom = sk + (dk1 + dk - 2.0f * sk) * xi * om;
        const float ynum = sk * xi * xi + dk * xi * om;
        const float yv = yk + hk2 * __fdividef(ynum, denom);
        const float larg = dk1 * xi * xi + 2.0f * sk * xi * om + dk * om * om;
        const float ldet = 2.0f * __logf(sk) + __logf(larg) - 2.0f * __logf(denom);

        const float zval = inside ? yv : ud;
        ldacc += inside ? ldet : 0.0f;

        if (d == 0) zlo.x = zval; else if (d == 1) zlo.y = zval;
        else if (d == 2) zlo.z = zval; else if (d == 3) zlo.w = zval;
        else if (d == 4) zhi.x = zval; else if (d == 5) zhi.y = zval;
        else if (d == 6) zhi.z = zval; else zhi.w = zval;
    }

    ov[r * 4 + 2] = zlo;
    ov[r * 4 + 3] = zhi;

    // ---- logdet reduction: wave shuffle -> LDS -> one atomic per block ----
    #pragma unroll
    for (int off = 32; off > 0; off >>= 1) ldacc += __shfl_down(ldacc, off);
    if ((tid & 63) == 0) red[tid >> 6] = ldacc;
    __syncthreads();
    if (tid == 0) atomicAdd(ldsum_out, red[0] + red[1] + red[2] + red[3]);
}

extern "C" void kernel_launch(void* const* d_in, const int* in_sizes, int n_in,
                              void* d_out, int out_size, void* d_ws, size_t ws_size,
                              hipStream_t stream) {
    const float* x  = (const float*)d_in[0];
    const float* w0 = (const float*)d_in[1];
    const float* b0 = (const float*)d_in[2];
    const float* w1 = (const float*)d_in[3];
    const float* b1 = (const float*)d_in[4];
    const float* ww = (const float*)d_in[5];
    const float* bw = (const float*)d_in[6];
    const float* wh = (const float*)d_in[7];
    const float* bh = (const float*)d_in[8];
    const float* wd = (const float*)d_in[9];
    const float* bd = (const float*)d_in[10];

    float* out = (float*)d_out;
    float* ldp = out + (size_t)NROWS * 16;  // scalar logdet sum slot

    hipLaunchKernelGGL(nsf_zero, dim3(1), dim3(64), 0, stream, ldp);
    hipLaunchKernelGGL(nsf_main, dim3(NROWS / 256), dim3(256), 0, stream,
                       x, w0, b0, w1, b1, ww, bw, wh, bh, wd, bd, out, ldp);
}

// Round 3
// 457.745 us; speedup vs baseline: 1.1811x; 1.1811x over previous
//
#include <hip/hip_runtime.h>
#include <hip/hip_fp16.h>

#define NROWS 262144
#define HIDN 50
#define KK 10
#define TDIM 8
#define BB 3.0f

// zero the logdet accumulator slot (d_out is poisoned 0xAA before every timed launch)
__global__ void nsf_zero(float* __restrict__ p) {
    if (threadIdx.x == 0) *p = 0.0f;
}

__device__ __forceinline__ float fast_tanh(float a) {
    float e = __expf(2.0f * a);
    return 1.0f - __fdividef(2.0f, e + 1.0f);
}

// rational-quadratic spline epilogue for one dim: softmax/softplus + bin select + transform
__device__ __forceinline__ void spline_epilogue(
    float (&aw)[KK], float (&ah)[KK], float (&ad)[KK - 1],
    float ud, float& zval, float& ldacc)
{
    float mw = aw[0];
    #pragma unroll
    for (int i = 1; i < KK; ++i) mw = fmaxf(mw, aw[i]);
    float sw = 0.0f;
    #pragma unroll
    for (int i = 0; i < KK; ++i) { aw[i] = __expf(6.0f * (aw[i] - mw)); sw += aw[i]; }
    const float invw = __fdividef(1.0f, sw);

    float mh = ah[0];
    #pragma unroll
    for (int i = 1; i < KK; ++i) mh = fmaxf(mh, ah[i]);
    float sh = 0.0f;
    #pragma unroll
    for (int i = 0; i < KK; ++i) { ah[i] = __expf(6.0f * (ah[i] - mh)); sh += ah[i]; }
    const float invh = __fdividef(1.0f, sh);

    float sp[KK - 1];
    #pragma unroll
    for (int i = 0; i < KK - 1; ++i) {
        const float v = ad[i];
        sp[i] = fmaxf(v, 0.0f) + __logf(1.0f + __expf(-fabsf(v)));
    }

    const float uc = fminf(fmaxf(ud, -BB), BB);
    const bool inside = (ud > -BB) && (ud < BB);

    float cw = 0.0f, ch = 0.0f;
    float xprev = -BB, yprev = -BB, dprev = 1.0f;
    float xk = -BB, yk = -BB, wk = 1.0f, hk2 = 1.0f, dk = 1.0f, dk1 = 1.0f;
    #pragma unroll
    for (int i = 0; i < KK; ++i) {
        cw += aw[i] * invw;
        ch += ah[i] * invh;
        const float xnext = fmaf(6.0f, cw, -BB);
        const float ynext = fmaf(6.0f, ch, -BB);
        const float dnext = (i == KK - 1) ? 1.0f : sp[i];
        const bool c = (i == 0) || (uc >= xprev);
        if (c) { xk = xprev; yk = yprev; wk = xnext - xprev; hk2 = ynext - yprev; dk = dprev; dk1 = dnext; }
        xprev = xnext; yprev = ynext; dprev = dnext;
    }

    const float sk = __fdividef(hk2, wk);
    const float xi = __fdividef(uc - xk, wk);
    const float om = 1.0f - xi;
    const float denom = sk + (dk1 + dk - 2.0f * sk) * xi * om;
    const float ynum = sk * xi * xi + dk * xi * om;
    const float yv = yk + hk2 * __fdividef(ynum, denom);
    const float larg = dk1 * xi * xi + 2.0f * sk * xi * om + dk * om * om;
    const float ldet = 2.0f * __logf(sk) + __logf(larg) - 2.0f * __logf(denom);

    zval = inside ? yv : ud;
    ldacc += inside ? ldet : 0.0f;
}

// ============ Kernel A: h2 = tanh(tanh(zd@w0+b0)@w1+b1), fully register-resident ============
__global__ __launch_bounds__(256, 4) void nsf_hidden(
    const float* __restrict__ x,
    const float* __restrict__ w0, const float* __restrict__ b0,
    const float* __restrict__ w1, const float* __restrict__ b1,
    float* __restrict__ out, __half2* __restrict__ hws)
{
    const int r = blockIdx.x * 256 + threadIdx.x;
    const float4* xv = (const float4*)x;
    const float4 xv0 = xv[r * 4 + 0];
    const float4 xv1 = xv[r * 4 + 1];

    // passthrough of the 8 scale dims
    float4* ov = (float4*)out;
    ov[r * 4 + 0] = xv0;
    ov[r * 4 + 1] = xv1;

    float h1[HIDN];
    {
        float acc[HIDN];
        #pragma unroll
        for (int j = 0; j < HIDN; ++j) acc[j] = b0[j];
        const float z0[8] = {xv0.x, xv0.y, xv0.z, xv0.w, xv1.x, xv1.y, xv1.z, xv1.w};
        #pragma unroll
        for (int k = 0; k < 8; ++k) {
            const float zk = z0[k];
            #pragma unroll
            for (int j = 0; j < HIDN; ++j)
                acc[j] = fmaf(zk, w0[k * HIDN + j], acc[j]);
        }
        #pragma unroll
        for (int j = 0; j < HIDN; ++j) h1[j] = fast_tanh(acc[j]);
    }
    {
        float acc[HIDN];
        #pragma unroll
        for (int j = 0; j < HIDN; ++j) acc[j] = b1[j];
        #pragma unroll
        for (int k = 0; k < HIDN; ++k) {   // full unroll: static h1 indices, no LDS/spill
            const float hk = h1[k];
            #pragma unroll
            for (int j = 0; j < HIDN; ++j)
                acc[j] = fmaf(hk, w1[k * HIDN + j], acc[j]);
        }
        // store h2 as half2, [k2][row] layout -> coalesced 4B/lane
        #pragma unroll
        for (int j = 0; j < HIDN / 2; ++j)
            hws[j * NROWS + r] = __floats2half2_rn(fast_tanh(acc[2 * j]), fast_tanh(acc[2 * j + 1]));
    }
}

// ============ Kernel B: projections + spline, 2 dims per h-sweep, zero big LDS ============
__global__ __launch_bounds__(256, 4) void nsf_spline(
    const float* __restrict__ x, const __half2* __restrict__ hws,
    const float* __restrict__ ww, const float* __restrict__ bw,
    const float* __restrict__ wh, const float* __restrict__ bh,
    const float* __restrict__ wd, const float* __restrict__ bd,
    float* __restrict__ out, float* __restrict__ ldsum_out)
{
    __shared__ float red[4];
    const int tid = threadIdx.x;
    const int r = blockIdx.x * 256 + tid;

    const float4* xv = (const float4*)x;
    const float4 xu0 = xv[r * 4 + 2];
    const float4 xu1 = xv[r * 4 + 3];
    const float uarr[8] = {xu0.x, xu0.y, xu0.z, xu0.w, xu1.x, xu1.y, xu1.z, xu1.w};

    float zarr[8];
    float ldacc = 0.0f;

    #pragma unroll
    for (int dp = 0; dp < 4; ++dp) {       // 2 dims per sweep
        const int d0 = 2 * dp, d1 = 2 * dp + 1;
        float aw0[KK], ah0[KK], ad0[KK - 1];
        float aw1[KK], ah1[KK], ad1[KK - 1];
        #pragma unroll
        for (int i = 0; i < KK; ++i)     { aw0[i] = bw[d0 * KK + i]; aw1[i] = bw[d1 * KK + i]; }
        #pragma unroll
        for (int i = 0; i < KK; ++i)     { ah0[i] = bh[d0 * KK + i]; ah1[i] = bh[d1 * KK + i]; }
        #pragma unroll
        for (int i = 0; i < KK - 1; ++i) { ad0[i] = bd[d0 * (KK - 1) + i]; ad1[i] = bd[d1 * (KK - 1) + i]; }

        #pragma unroll 5
        for (int k2 = 0; k2 < HIDN / 2; ++k2) {
            const __half2 p = hws[k2 * NROWS + r];
            const float ha = __low2float(p);
            const float hb = __high2float(p);
            const int ka = 2 * k2, kb2 = 2 * k2 + 1;
            const float* wwa = ww + ka * (TDIM * KK);
            const float* wha = wh + ka * (TDIM * KK);
            const float* wda = wd + ka * (TDIM * (KK - 1));
            const float* wwb = ww + kb2 * (TDIM * KK);
            const float* whb = wh + kb2 * (TDIM * KK);
            const float* wdb = wd + kb2 * (TDIM * (KK - 1));
            #pragma unroll
            for (int i = 0; i < KK; ++i) {
                aw0[i] = fmaf(ha, wwa[d0 * KK + i], aw0[i]);
                aw1[i] = fmaf(ha, wwa[d1 * KK + i], aw1[i]);
                aw0[i] = fmaf(hb, wwb[d0 * KK + i], aw0[i]);
                aw1[i] = fmaf(hb, wwb[d1 * KK + i], aw1[i]);
            }
            #pragma unroll
            for (int i = 0; i < KK; ++i) {
                ah0[i] = fmaf(ha, wha[d0 * KK + i], ah0[i]);
                ah1[i] = fmaf(ha, wha[d1 * KK + i], ah1[i]);
                ah0[i] = fmaf(hb, whb[d0 * KK + i], ah0[i]);
                ah1[i] = fmaf(hb, whb[d1 * KK + i], ah1[i]);
            }
            #pragma unroll
            for (int i = 0; i < KK - 1; ++i) {
                ad0[i] = fmaf(ha, wda[d0 * (KK - 1) + i], ad0[i]);
                ad1[i] = fmaf(ha, wda[d1 * (KK - 1) + i], ad1[i]);
                ad0[i] = fmaf(hb, wdb[d0 * (KK - 1) + i], ad0[i]);
                ad1[i] = fmaf(hb, wdb[d1 * (KK - 1) + i], ad1[i]);
            }
        }

        spline_epilogue(aw0, ah0, ad0, uarr[d0], zarr[d0], ldacc);
        spline_epilogue(aw1, ah1, ad1, uarr[d1], zarr[d1], ldacc);
    }

    float4* ov = (float4*)out;
    ov[r * 4 + 2] = make_float4(zarr[0], zarr[1], zarr[2], zarr[3]);
    ov[r * 4 + 3] = make_float4(zarr[4], zarr[5], zarr[6], zarr[7]);

    #pragma unroll
    for (int off = 32; off > 0; off >>= 1) ldacc += __shfl_down(ldacc, off);
    if ((tid & 63) == 0) red[tid >> 6] = ldacc;
    __syncthreads();
    if (tid == 0) atomicAdd(ldsum_out, red[0] + red[1] + red[2] + red[3]);
}

// ============ Fallback: R1 fused kernel (used only if ws_size too small) ============
__global__ __launch_bounds__(256) void nsf_fused(
    const float* __restrict__ x,
    const float* __restrict__ w0, const float* __restrict__ b0,
    const float* __restrict__ w1, const float* __restrict__ b1,
    const float* __restrict__ ww, const float* __restrict__ bw,
    const float* __restrict__ wh, const float* __restrict__ bh,
    const float* __restrict__ wd, const float* __restrict__ bd,
    float* __restrict__ out, float* __restrict__ ldsum_out)
{
    __shared__ float hbuf[256 * 51];
    __shared__ float red[4];
    const int tid = threadIdx.x;
    const int r = blockIdx.x * 256 + tid;

    const float4* xv = (const float4*)x;
    const float4 xv0 = xv[r * 4 + 0];
    const float4 xv1 = xv[r * 4 + 1];
    const float4 xv2 = xv[r * 4 + 2];
    const float4 xv3 = xv[r * 4 + 3];
    float4* ov = (float4*)out;
    ov[r * 4 + 0] = xv0;
    ov[r * 4 + 1] = xv1;

    float acc[HIDN];
    #pragma unroll
    for (int j = 0; j < HIDN; ++j) acc[j] = b0[j];
    {
        const float z0[8] = {xv0.x, xv0.y, xv0.z, xv0.w, xv1.x, xv1.y, xv1.z, xv1.w};
        #pragma unroll
        for (int k = 0; k < 8; ++k) {
            const float zk = z0[k];
            #pragma unroll
            for (int j = 0; j < HIDN; ++j)
                acc[j] = fmaf(zk, w0[k * HIDN + j], acc[j]);
        }
    }
    float* hrow = &hbuf[tid * 51];
    #pragma unroll
    for (int j = 0; j < HIDN; ++j) hrow[j] = fast_tanh(acc[j]);

    #pragma unroll
    for (int j = 0; j < HIDN; ++j) acc[j] = b1[j];
    #pragma unroll 2
    for (int k = 0; k < HIDN; ++k) {
        const float hk = hrow[k];
        #pragma unroll
        for (int j = 0; j < HIDN; ++j)
            acc[j] = fmaf(hk, w1[k * HIDN + j], acc[j]);
    }
    #pragma unroll
    for (int j = 0; j < HIDN; ++j) hrow[j] = fast_tanh(acc[j]);

    float ldacc = 0.0f;
    #pragma unroll 1
    for (int d = 0; d < TDIM; ++d) {
        float aw[KK], ah[KK], ad[KK - 1];
        #pragma unroll
        for (int i = 0; i < KK; ++i)     aw[i] = bw[d * KK + i];
        #pragma unroll
        for (int i = 0; i < KK; ++i)     ah[i] = bh[d * KK + i];
        #pragma unroll
        for (int i = 0; i < KK - 1; ++i) ad[i] = bd[d * (KK - 1) + i];
        #pragma unroll 2
        for (int k = 0; k < HIDN; ++k) {
            const float hk = hrow[k];
            const float* wwr = ww + k * (TDIM * KK) + d * KK;
            const float* whr = wh + k * (TDIM * KK) + d * KK;
            const float* wdr = wd + k * (TDIM * (KK - 1)) + d * (KK - 1);
            #pragma unroll
            for (int i = 0; i < KK; ++i)     aw[i] = fmaf(hk, wwr[i], aw[i]);
            #pragma unroll
            for (int i = 0; i < KK; ++i)     ah[i] = fmaf(hk, whr[i], ah[i]);
            #pragma unroll
            for (int i = 0; i < KK - 1; ++i) ad[i] = fmaf(hk, wdr[i], ad[i]);
        }
        const float4 vsel = (d < 4) ? xv2 : xv3;
        const int dd = d & 3;
        const float ud = (dd == 0) ? vsel.x : (dd == 1) ? vsel.y : (dd == 2) ? vsel.z : vsel.w;
        float zval;
        spline_epilogue(aw, ah, ad, ud, zval, ldacc);
        out[r * 16 + 8 + d] = zval;
    }

    #pragma unroll
    for (int off = 32; off > 0; off >>= 1) ldacc += __shfl_down(ldacc, off);
    if ((tid & 63) == 0) red[tid >> 6] = ldacc;
    __syncthreads();
    if (tid == 0) atomicAdd(ldsum_out, red[0] + red[1] + red[2] + red[3]);
}

extern "C" void kernel_launch(void* const* d_in, const int* in_sizes, int n_in,
                              void* d_out, int out_size, void* d_ws, size_t ws_size,
                              hipStream_t stream) {
    const float* x  = (const float*)d_in[0];
    const float* w0 = (const float*)d_in[1];
    const float* b0 = (const float*)d_in[2];
    const float* w1 = (const float*)d_in[3];
    const float* b1 = (const float*)d_in[4];
    const float* ww = (const float*)d_in[5];
    const float* bw = (const float*)d_in[6];
    const float* wh = (const float*)d_in[7];
    const float* bh = (const float*)d_in[8];
    const float* wd = (const float*)d_in[9];
    const float* bd = (const float*)d_in[10];

    float* out = (float*)d_out;
    float* ldp = out + (size_t)NROWS * 16;  // scalar logdet sum slot

    hipLaunchKernelGGL(nsf_zero, dim3(1), dim3(64), 0, stream, ldp);

    const size_t need = (size_t)(HIDN / 2) * NROWS * sizeof(__half2);  // 26.2 MB
    if (ws_size >= need) {
        __half2* hws = (__half2*)d_ws;
        hipLaunchKernelGGL(nsf_hidden, dim3(NROWS / 256), dim3(256), 0, stream,
                           x, w0, b0, w1, b1, out, hws);
        hipLaunchKernelGGL(nsf_spline, dim3(NROWS / 256), dim3(256), 0, stream,
                           x, hws, ww, bw, wh, bh, wd, bd, out, ldp);
    } else {
        hipLaunchKernelGGL(nsf_fused, dim3(NROWS / 256), dim3(256), 0, stream,
                           x, w0, b0, w1, b1, ww, bw, wh, bh, wd, bd, out, ldp);
    }
}

// Round 4
// 260.949 us; speedup vs baseline: 2.0718x; 1.7542x over previous
//
#include <hip/hip_runtime.h>
#include <hip/hip_fp16.h>

#define NROWS 262144
#define HIDN 50
#define KK 10
#define TDIM 8
#define BB 3.0f
#define HSTRIDE 27  // half2 words per thread row; odd -> conflict-free (2-way alias only)

// zero the logdet accumulator slot (d_out is poisoned 0xAA before every timed launch)
__global__ void nsf_zero(float* __restrict__ p) {
    if (threadIdx.x == 0) *p = 0.0f;
}

__device__ __forceinline__ float fast_tanh(float a) {
    float e = __expf(2.0f * a);
    return 1.0f - __fdividef(2.0f, e + 1.0f);
}

__global__ __launch_bounds__(256, 5) void nsf_main(
    const float* __restrict__ x,
    const float* __restrict__ w0, const float* __restrict__ b0,
    const float* __restrict__ w1, const float* __restrict__ b1,
    const float* __restrict__ ww, const float* __restrict__ bw,
    const float* __restrict__ wh, const float* __restrict__ bh,
    const float* __restrict__ wd, const float* __restrict__ bd,
    float* __restrict__ out, float* __restrict__ ldsum_out)
{
    __shared__ __half2 hbuf[256 * HSTRIDE];
    __shared__ float red[4];

    const int tid = threadIdx.x;
    const int r = blockIdx.x * 256 + tid;

    const float4* xv = (const float4*)x;
    const float4 xv0 = xv[r * 4 + 0];
    const float4 xv1 = xv[r * 4 + 1];

    // passthrough of the 8 scale dims
    float4* ov = (float4*)out;
    ov[r * 4 + 0] = xv0;
    ov[r * 4 + 1] = xv1;

    float acc[HIDN];
    __half2* hrow = &hbuf[tid * HSTRIDE];

    // ---- phase 1: h1 = tanh(zd @ w0 + b0) ----
    #pragma unroll
    for (int j = 0; j < HIDN; ++j) acc[j] = b0[j];
    {
        const float z0[8] = {xv0.x, xv0.y, xv0.z, xv0.w, xv1.x, xv1.y, xv1.z, xv1.w};
        #pragma unroll
        for (int k = 0; k < 8; ++k) {
            const float zk = z0[k];
            #pragma unroll
            for (int j = 0; j < HIDN; ++j)
                acc[j] = fmaf(zk, w0[k * HIDN + j], acc[j]);
        }
    }
    #pragma unroll
    for (int j = 0; j < HIDN / 2; ++j)
        hrow[j] = __floats2half2_rn(fast_tanh(acc[2 * j]), fast_tanh(acc[2 * j + 1]));

    // ---- phase 2: h2 = tanh(h1 @ w1 + b1) ----
    #pragma unroll
    for (int j = 0; j < HIDN; ++j) acc[j] = b1[j];
    #pragma unroll 1
    for (int k2 = 0; k2 < HIDN / 2; ++k2) {
        const __half2 p = hrow[k2];
        const float ha = __low2float(p);
        const float hb = __high2float(p);
        const float* wr = w1 + (2 * k2) * HIDN;
        #pragma unroll
        for (int j = 0; j < HIDN; ++j) acc[j] = fmaf(ha, wr[j], acc[j]);
        #pragma unroll
        for (int j = 0; j < HIDN; ++j) acc[j] = fmaf(hb, wr[HIDN + j], acc[j]);
    }
    #pragma unroll
    for (int j = 0; j < HIDN / 2; ++j)
        hrow[j] = __floats2half2_rn(fast_tanh(acc[2 * j]), fast_tanh(acc[2 * j + 1]));

    // u values loaded late to reduce peak pressure during phases 1-2
    const float4 xu0 = xv[r * 4 + 2];
    const float4 xu1 = xv[r * 4 + 3];

    // ---- phase 3: per transformed dim (rolled d, rolled k) ----
    float ldacc = 0.0f;
    #pragma unroll 1
    for (int d = 0; d < TDIM; ++d) {
        float aw[KK], ah[KK], ad[KK - 1];
        #pragma unroll
        for (int i = 0; i < KK; ++i)     aw[i] = bw[d * KK + i];
        #pragma unroll
        for (int i = 0; i < KK; ++i)     ah[i] = bh[d * KK + i];
        #pragma unroll
        for (int i = 0; i < KK - 1; ++i) ad[i] = bd[d * (KK - 1) + i];

        #pragma unroll 2
        for (int k2 = 0; k2 < HIDN / 2; ++k2) {
            const __half2 p = hrow[k2];
            const float hv[2] = {__low2float(p), __high2float(p)};
            #pragma unroll
            for (int s = 0; s < 2; ++s) {
                const int k = 2 * k2 + s;
                const float hk = hv[s];
                const float* wwr = ww + k * (TDIM * KK) + d * KK;
                const float* whr = wh + k * (TDIM * KK) + d * KK;
                const float* wdr = wd + k * (TDIM * (KK - 1)) + d * (KK - 1);
                #pragma unroll
                for (int i = 0; i < KK; ++i)     aw[i] = fmaf(hk, wwr[i], aw[i]);
                #pragma unroll
                for (int i = 0; i < KK; ++i)     ah[i] = fmaf(hk, whr[i], ah[i]);
                #pragma unroll
                for (int i = 0; i < KK - 1; ++i) ad[i] = fmaf(hk, wdr[i], ad[i]);
            }
        }

        // softmax over K for widths (logits = 6*aw)
        float mw = aw[0];
        #pragma unroll
        for (int i = 1; i < KK; ++i) mw = fmaxf(mw, aw[i]);
        float sw = 0.0f;
        #pragma unroll
        for (int i = 0; i < KK; ++i) { aw[i] = __expf(6.0f * (aw[i] - mw)); sw += aw[i]; }
        const float invw = __fdividef(1.0f, sw);

        // softmax over K for heights
        float mh = ah[0];
        #pragma unroll
        for (int i = 1; i < KK; ++i) mh = fmaxf(mh, ah[i]);
        float sh = 0.0f;
        #pragma unroll
        for (int i = 0; i < KK; ++i) { ah[i] = __expf(6.0f * (ah[i] - mh)); sh += ah[i]; }
        const float invh = __fdividef(1.0f, sh);

        // softplus derivatives
        float sp[KK - 1];
        #pragma unroll
        for (int i = 0; i < KK - 1; ++i) {
            const float v = ad[i];
            sp[i] = fmaxf(v, 0.0f) + __logf(1.0f + __expf(-fabsf(v)));
        }

        // u for this dim
        const float4 vsel = (d < 4) ? xu0 : xu1;
        const int dd = d & 3;
        const float ud = (dd == 0) ? vsel.x : (dd == 1) ? vsel.y : (dd == 2) ? vsel.z : vsel.w;
        const float uc = fminf(fmaxf(ud, -BB), BB);
        const bool inside = (ud > -BB) && (ud < BB);

        // streaming bin search + parameter select
        float cw = 0.0f, ch = 0.0f;
        float xprev = -BB, yprev = -BB, dprev = 1.0f;
        float xk = -BB, yk = -BB, wk = 1.0f, hk2 = 1.0f, dk = 1.0f, dk1 = 1.0f;
        #pragma unroll
        for (int i = 0; i < KK; ++i) {
            cw += aw[i] * invw;
            ch += ah[i] * invh;
            const float xnext = fmaf(6.0f, cw, -BB);
            const float ynext = fmaf(6.0f, ch, -BB);
            const float dnext = (i == KK - 1) ? 1.0f : sp[i];
            const bool c = (i == 0) || (uc >= xprev);
            if (c) { xk = xprev; yk = yprev; wk = xnext - xprev; hk2 = ynext - yprev; dk = dprev; dk1 = dnext; }
            xprev = xnext; yprev = ynext; dprev = dnext;
        }

        // rational-quadratic spline
        const float sk = __fdividef(hk2, wk);
        const float xi = __fdividef(uc - xk, wk);
        const float om = 1.0f - xi;
        const float denom = sk + (dk1 + dk - 2.0f * sk) * xi * om;
        const float ynum = sk * xi * xi + dk * xi * om;
        const float yv = yk + hk2 * __fdividef(ynum, denom);
        const float larg = dk1 * xi * xi + 2.0f * sk * xi * om + dk * om * om;
        const float ldet = 2.0f * __logf(sk) + __logf(larg) - 2.0f * __logf(denom);

        out[r * 16 + 8 + d] = inside ? yv : ud;
        ldacc += inside ? ldet : 0.0f;
    }

    // ---- logdet reduction: wave shuffle -> LDS -> one atomic per block ----
    #pragma unroll
    for (int off = 32; off > 0; off >>= 1) ldacc += __shfl_down(ldacc, off);
    if ((tid & 63) == 0) red[tid >> 6] = ldacc;
    __syncthreads();
    if (tid == 0) atomicAdd(ldsum_out, red[0] + red[1] + red[2] + red[3]);
}

extern "C" void kernel_launch(void* const* d_in, const int* in_sizes, int n_in,
                              void* d_out, int out_size, void* d_ws, size_t ws_size,
                              hipStream_t stream) {
    const float* x  = (const float*)d_in[0];
    const float* w0 = (const float*)d_in[1];
    const float* b0 = (const float*)d_in[2];
    const float* w1 = (const float*)d_in[3];
    const float* b1 = (const float*)d_in[4];
    const float* ww = (const float*)d_in[5];
    const float* bw = (const float*)d_in[6];
    const float* wh = (const float*)d_in[7];
    const float* bh = (const float*)d_in[8];
    const float* wd = (const float*)d_in[9];
    const float* bd = (const float*)d_in[10];

    float* out = (float*)d_out;
    float* ldp = out + (size_t)NROWS * 16;  // scalar logdet sum slot

    hipLaunchKernelGGL(nsf_zero, dim3(1), dim3(64), 0, stream, ldp);
    hipLaunchKernelGGL(nsf_main, dim3(NROWS / 256), dim3(256), 0, stream,
                       x, w0, b0, w1, b1, ww, bw, wh, bh, wd, bd, out, ldp);
}

// Round 5
// 231.527 us; speedup vs baseline: 2.3351x; 1.1271x over previous
//
#include <hip/hip_runtime.h>
#include <hip/hip_fp16.h>

#define NROWS 262144
#define HIDN 50
#define KK 10
#define TDIM 8
#define BB 3.0f
#define HSTRIDE 27  // half2 words per thread row; odd -> conflict-free (2-way alias only)

typedef _Float16 h2vec __attribute__((ext_vector_type(2)));

// ws layout (h2vec units): w1p[1250] | wwp[2000] | whp[2000] | wdp[1800]
#define W1P_OFF 0
#define WWP_OFF 1250
#define WHP_OFF 3250
#define WDP_OFF 5250
#define WS_TOTAL 7050

__device__ __forceinline__ float fdot2(h2vec a, h2vec b, float c) {
#if __has_builtin(__builtin_amdgcn_fdot2)
    return __builtin_amdgcn_fdot2(a, b, c, false);
#else
    return c + (float)a[0] * (float)b[0] + (float)a[1] * (float)b[1];
#endif
}

__device__ __forceinline__ float fast_tanh(float a) {
    float e = __expf(2.0f * a);
    return 1.0f - __fdividef(2.0f, e + 1.0f);
}

// prep: pack weights as half2 pairs along k (w[2k2][c], w[2k2+1][c]); also zero logdet slot
__global__ __launch_bounds__(256) void nsf_prep(
    const float* __restrict__ w1, const float* __restrict__ ww,
    const float* __restrict__ wh, const float* __restrict__ wd,
    h2vec* __restrict__ wsv, float* __restrict__ ldp)
{
    const int t = blockIdx.x * 256 + threadIdx.x;
    if (t == 0) *ldp = 0.0f;
    if (t < 1250) {                       // w1p: [k2][j], j<50
        const int k2 = t / 50, j = t - k2 * 50;
        wsv[W1P_OFF + t] = h2vec{(_Float16)w1[(2 * k2) * 50 + j], (_Float16)w1[(2 * k2 + 1) * 50 + j]};
    } else if (t < 3250) {                // wwp: [k2][c], c<80
        const int p = t - 1250, k2 = p / 80, c = p - k2 * 80;
        wsv[t] = h2vec{(_Float16)ww[(2 * k2) * 80 + c], (_Float16)ww[(2 * k2 + 1) * 80 + c]};
    } else if (t < 5250) {                // whp
        const int p = t - 3250, k2 = p / 80, c = p - k2 * 80;
        wsv[t] = h2vec{(_Float16)wh[(2 * k2) * 80 + c], (_Float16)wh[(2 * k2 + 1) * 80 + c]};
    } else if (t < WS_TOTAL) {            // wdp: [k2][c], c<72
        const int p = t - 5250, k2 = p / 72, c = p - k2 * 72;
        wsv[t] = h2vec{(_Float16)wd[(2 * k2) * 72 + c], (_Float16)wd[(2 * k2 + 1) * 72 + c]};
    }
}

__global__ __launch_bounds__(256, 5) void nsf_main(
    const float* __restrict__ x,
    const float* __restrict__ w0, const float* __restrict__ b0,
    const float* __restrict__ b1,
    const h2vec* __restrict__ wsv,
    const float* __restrict__ bw, const float* __restrict__ bh, const float* __restrict__ bd,
    float* __restrict__ out, float* __restrict__ ldsum_out)
{
    __shared__ h2vec hbuf[256 * HSTRIDE];
    __shared__ float red[4];

    const int tid = threadIdx.x;
    const int r = blockIdx.x * 256 + tid;

    const float4* xv = (const float4*)x;
    const float4 xv0 = xv[r * 4 + 0];
    const float4 xv1 = xv[r * 4 + 1];

    // passthrough of the 8 scale dims
    float4* ov = (float4*)out;
    ov[r * 4 + 0] = xv0;
    ov[r * 4 + 1] = xv1;

    float acc[HIDN];
    h2vec* hrow = &hbuf[tid * HSTRIDE];

    // ---- phase 1: h1 = tanh(zd @ w0 + b0), fp32 ----
    #pragma unroll
    for (int j = 0; j < HIDN; ++j) acc[j] = b0[j];
    {
        const float z0[8] = {xv0.x, xv0.y, xv0.z, xv0.w, xv1.x, xv1.y, xv1.z, xv1.w};
        #pragma unroll
        for (int k = 0; k < 8; ++k) {
            const float zk = z0[k];
            #pragma unroll
            for (int j = 0; j < HIDN; ++j)
                acc[j] = fmaf(zk, w0[k * HIDN + j], acc[j]);
        }
    }
    #pragma unroll
    for (int j = 0; j < HIDN / 2; ++j)
        hrow[j] = h2vec{(_Float16)fast_tanh(acc[2 * j]), (_Float16)fast_tanh(acc[2 * j + 1])};

    // ---- phase 2: h2 = tanh(h1 @ w1 + b1), f16 dot2 with f32 accum ----
    #pragma unroll
    for (int j = 0; j < HIDN; ++j) acc[j] = b1[j];
    #pragma unroll 1
    for (int k2 = 0; k2 < HIDN / 2; ++k2) {
        const h2vec hp = hrow[k2];
        const h2vec* wr = wsv + W1P_OFF + k2 * HIDN;
        #pragma unroll
        for (int j = 0; j < HIDN; ++j) acc[j] = fdot2(hp, wr[j], acc[j]);
    }
    #pragma unroll
    for (int j = 0; j < HIDN / 2; ++j)
        hrow[j] = h2vec{(_Float16)fast_tanh(acc[2 * j]), (_Float16)fast_tanh(acc[2 * j + 1])};

    // u values loaded late to reduce peak pressure during phases 1-2
    const float4 xu0 = xv[r * 4 + 2];
    const float4 xu1 = xv[r * 4 + 3];

    // ---- phase 3: per transformed dim (rolled d), f16 dot2 projections ----
    float ldacc = 0.0f;
    #pragma unroll 1
    for (int d = 0; d < TDIM; ++d) {
        float aw[KK], ah[KK], ad[KK - 1];
        #pragma unroll
        for (int i = 0; i < KK; ++i)     aw[i] = bw[d * KK + i];
        #pragma unroll
        for (int i = 0; i < KK; ++i)     ah[i] = bh[d * KK + i];
        #pragma unroll
        for (int i = 0; i < KK - 1; ++i) ad[i] = bd[d * (KK - 1) + i];

        #pragma unroll 5
        for (int k2 = 0; k2 < HIDN / 2; ++k2) {
            const h2vec hp = hrow[k2];
            const h2vec* wwr = wsv + WWP_OFF + k2 * (TDIM * KK) + d * KK;
            const h2vec* whr = wsv + WHP_OFF + k2 * (TDIM * KK) + d * KK;
            const h2vec* wdr = wsv + WDP_OFF + k2 * (TDIM * (KK - 1)) + d * (KK - 1);
            #pragma unroll
            for (int i = 0; i < KK; ++i)     aw[i] = fdot2(hp, wwr[i], aw[i]);
            #pragma unroll
            for (int i = 0; i < KK; ++i)     ah[i] = fdot2(hp, whr[i], ah[i]);
            #pragma unroll
            for (int i = 0; i < KK - 1; ++i) ad[i] = fdot2(hp, wdr[i], ad[i]);
        }

        // softmax over K for widths (logits = 6*aw)
        float mw = aw[0];
        #pragma unroll
        for (int i = 1; i < KK; ++i) mw = fmaxf(mw, aw[i]);
        float sw = 0.0f;
        #pragma unroll
        for (int i = 0; i < KK; ++i) { aw[i] = __expf(6.0f * (aw[i] - mw)); sw += aw[i]; }
        const float invw = __fdividef(1.0f, sw);

        // softmax over K for heights
        float mh = ah[0];
        #pragma unroll
        for (int i = 1; i < KK; ++i) mh = fmaxf(mh, ah[i]);
        float sh = 0.0f;
        #pragma unroll
        for (int i = 0; i < KK; ++i) { ah[i] = __expf(6.0f * (ah[i] - mh)); sh += ah[i]; }
        const float invh = __fdividef(1.0f, sh);

        // softplus derivatives
        float sp[KK - 1];
        #pragma unroll
        for (int i = 0; i < KK - 1; ++i) {
            const float v = ad[i];
            sp[i] = fmaxf(v, 0.0f) + __logf(1.0f + __expf(-fabsf(v)));
        }

        // u for this dim
        const float4 vsel = (d < 4) ? xu0 : xu1;
        const int dd = d & 3;
        const float ud = (dd == 0) ? vsel.x : (dd == 1) ? vsel.y : (dd == 2) ? vsel.z : vsel.w;
        const float uc = fminf(fmaxf(ud, -BB), BB);
        const bool inside = (ud > -BB) && (ud < BB);

        // streaming bin search + parameter select
        float cw = 0.0f, ch = 0.0f;
        float xprev = -BB, yprev = -BB, dprev = 1.0f;
        float xk = -BB, yk = -BB, wk = 1.0f, hk2 = 1.0f, dk = 1.0f, dk1 = 1.0f;
        #pragma unroll
        for (int i = 0; i < KK; ++i) {
            cw += aw[i] * invw;
            ch += ah[i] * invh;
            const float xnext = fmaf(6.0f, cw, -BB);
            const float ynext = fmaf(6.0f, ch, -BB);
            const float dnext = (i == KK - 1) ? 1.0f : sp[i];
            const bool c = (i == 0) || (uc >= xprev);
            if (c) { xk = xprev; yk = yprev; wk = xnext - xprev; hk2 = ynext - yprev; dk = dprev; dk1 = dnext; }
            xprev = xnext; yprev = ynext; dprev = dnext;
        }

        // rational-quadratic spline
        const float sk = __fdividef(hk2, wk);
        const float xi = __fdividef(uc - xk, wk);
        const float om = 1.0f - xi;
        const float denom = sk + (dk1 + dk - 2.0f * sk) * xi * om;
        const float ynum = sk * xi * xi + dk * xi * om;
        const float yv = yk + hk2 * __fdividef(ynum, denom);
        const float larg = dk1 * xi * xi + 2.0f * sk * xi * om + dk * om * om;
        const float ldet = 2.0f * __logf(sk) + __logf(larg) - 2.0f * __logf(denom);

        out[r * 16 + 8 + d] = inside ? yv : ud;
        ldacc += inside ? ldet : 0.0f;
    }

    // ---- logdet reduction: wave shuffle -> LDS -> one atomic per block ----
    #pragma unroll
    for (int off = 32; off > 0; off >>= 1) ldacc += __shfl_down(ldacc, off);
    if ((tid & 63) == 0) red[tid >> 6] = ldacc;
    __syncthreads();
    if (tid == 0) atomicAdd(ldsum_out, red[0] + red[1] + red[2] + red[3]);
}

extern "C" void kernel_launch(void* const* d_in, const int* in_sizes, int n_in,
                              void* d_out, int out_size, void* d_ws, size_t ws_size,
                              hipStream_t stream) {
    const float* x  = (const float*)d_in[0];
    const float* w0 = (const float*)d_in[1];
    const float* b0 = (const float*)d_in[2];
    const float* w1 = (const float*)d_in[3];
    const float* b1 = (const float*)d_in[4];
    const float* ww = (const float*)d_in[5];
    const float* bw = (const float*)d_in[6];
    const float* wh = (const float*)d_in[7];
    const float* bh = (const float*)d_in[8];
    const float* wd = (const float*)d_in[9];
    const float* bd = (const float*)d_in[10];

    float* out = (float*)d_out;
    float* ldp = out + (size_t)NROWS * 16;  // scalar logdet sum slot
    h2vec* wsv = (h2vec*)d_ws;              // 28.2 KB packed f16 weights

    hipLaunchKernelGGL(nsf_prep, dim3((WS_TOTAL + 255) / 256), dim3(256), 0, stream,
                       w1, ww, wh, wd, wsv, ldp);
    hipLaunchKernelGGL(nsf_main, dim3(NROWS / 256), dim3(256), 0, stream,
                       x, w0, b0, b1, wsv, bw, bh, bd, out, ldp);
}

// Round 6
// 210.100 us; speedup vs baseline: 2.5732x; 1.1020x over previous
//
#include <hip/hip_runtime.h>

#define NROWS 262144
#define KK 10
#define BB 3.0f
#define PSTRIDE 20                 // f16 units per proj column (even -> 8B-aligned b64 writes)
#define SEGF16 (232 * PSTRIDE)     // 4640 f16 = 9280 B per wave-private LDS segment

typedef _Float16 v8h __attribute__((ext_vector_type(8)));
typedef _Float16 v4h __attribute__((ext_vector_type(4)));
typedef float v4f __attribute__((ext_vector_type(4)));

// d_ws layout: v8h B-fragments: W0[4*64] | W1[2*4*64] | WC[2*15*64] ; then 64 f32 logdet slots
#define W0_OFF 0
#define W1_OFF 256
#define WC_OFF 768
#define FRAG_TOTAL 2688

__device__ __forceinline__ float fast_tanh(float a) {
    float e = __expf(2.0f * a);
    return 1.0f - __fdividef(2.0f, e + 1.0f);
}

// ---- prep: pack B-fragments (B[k=quad*8+j][n=lane&15]) for all three matmuls; zero slots ----
__global__ __launch_bounds__(256) void nsf_prep(
    const float* __restrict__ w0, const float* __restrict__ w1,
    const float* __restrict__ ww, const float* __restrict__ wh, const float* __restrict__ wd,
    v8h* __restrict__ wsv, float* __restrict__ slots)
{
    const int t = blockIdx.x * 256 + threadIdx.x;
    if (t < 64) slots[t] = 0.0f;
    if (t >= FRAG_TOTAL) return;

    v8h v;
    #pragma unroll
    for (int j = 0; j < 8; ++j) v[j] = (_Float16)0.0f;

    if (t < W1_OFF) {                       // W0: 8x50 padded to K=32, 4 col tiles
        const int tile = t >> 6, lane = t & 63, q = lane >> 4, n = tile * 16 + (lane & 15);
        #pragma unroll
        for (int j = 0; j < 8; ++j) {
            const int k = q * 8 + j;
            if (k < 8 && n < 50) v[j] = (_Float16)w0[k * 50 + n];
        }
    } else if (t < WC_OFF) {                // W1: 50x50, 2 k-steps, 4 col tiles
        int p = t - W1_OFF;
        const int step = p >> 8; p &= 255;
        const int tile = p >> 6, lane = p & 63, q = lane >> 4, n = tile * 16 + (lane & 15);
        #pragma unroll
        for (int j = 0; j < 8; ++j) {
            const int k = step * 32 + q * 8 + j;
            if (k < 50 && n < 50) v[j] = (_Float16)w1[k * 50 + n];
        }
    } else {                                // WC = [ww|wh|wd]: 50x232, 2 k-steps, 15 col tiles
        int p = t - WC_OFF;
        const int step = p / 960; p -= step * 960;
        const int tile = p >> 6, lane = p & 63, q = lane >> 4, c = tile * 16 + (lane & 15);
        #pragma unroll
        for (int j = 0; j < 8; ++j) {
            const int k = step * 32 + q * 8 + j;
            if (k < 50 && c < 232)
                v[j] = (_Float16)(c < 80 ? ww[k * 80 + c]
                                : c < 160 ? wh[k * 80 + (c - 80)]
                                          : wd[k * 72 + (c - 160)]);
        }
    }
    wsv[t] = v;
}

// ---- main: 1 wave = 16 rows; MFMA for all matmuls; wave-private LDS; no __syncthreads ----
__global__ __launch_bounds__(256, 4) void nsf_main(
    const float* __restrict__ x,
    const float* __restrict__ b0, const float* __restrict__ b1,
    const float* __restrict__ bw, const float* __restrict__ bh, const float* __restrict__ bd,
    const v8h* __restrict__ wsv,
    float* __restrict__ out, float* __restrict__ slots)
{
    __shared__ __align__(16) _Float16 smem[4 * SEGF16];   // 37120 B -> 4 blocks/CU
    const int tid = threadIdx.x, wave = tid >> 6, lane = tid & 63;
    const int q = lane >> 4, l15 = lane & 15;
    _Float16* seg = &smem[wave * SEGF16];
    const int R0 = blockIdx.x * 64 + wave * 16;           // first row of this wave's tile

    const float4* xv = (const float4*)x;
    float4* ov = (float4*)out;

    // passthrough of the 8 scale dims (lanes 0..31: 2 float4 per row)
    if (lane < 32) {
        const int g = R0 + (lane >> 1);
        const int part = lane & 1;
        ov[g * 4 + part] = xv[g * 4 + part];
    }

    // ---- phase 0: zd A-fragment (k<8 real, rest zero -> only quad 0 lanes load) ----
    v8h a;
    #pragma unroll
    for (int j = 0; j < 8; ++j) a[j] = (_Float16)0.0f;
    if (lane < 16) {   // q==0, m=lane
        const int g = R0 + lane;
        const float4 f0 = xv[g * 4 + 0];
        const float4 f1 = xv[g * 4 + 1];
        a[0] = (_Float16)f0.x; a[1] = (_Float16)f0.y; a[2] = (_Float16)f0.z; a[3] = (_Float16)f0.w;
        a[4] = (_Float16)f1.x; a[5] = (_Float16)f1.y; a[6] = (_Float16)f1.z; a[7] = (_Float16)f1.w;
    }

    // ---- phase 1: h1 = tanh(zd @ w0 + b0) -> LDS row-major [m][c], stride 72 f16 ----
    #pragma unroll
    for (int t = 0; t < 4; ++t) {
        const v8h b = wsv[W0_OFF + t * 64 + lane];
        v4f c = __builtin_amdgcn_mfma_f32_16x16x32_f16(a, b, (v4f)(0.0f), 0, 0, 0);
        const int n = t * 16 + l15;
        const float bias = (n < 50) ? b0[n] : 0.0f;
        #pragma unroll
        for (int rg = 0; rg < 4; ++rg)
            seg[(q * 4 + rg) * 72 + n] = (_Float16)fast_tanh(c[rg] + bias);
    }

    // ---- phase 2: h2 = tanh(h1 @ w1 + b1) ----
    {
        const v8h A0 = *(const v8h*)&seg[l15 * 72 + q * 8];        // k = q*8+j
        const v8h A1 = *(const v8h*)&seg[l15 * 72 + 32 + q * 8];   // k = 32+q*8+j
        #pragma unroll
        for (int t = 0; t < 4; ++t) {
            const v8h bf0 = wsv[W1_OFF + t * 64 + lane];
            const v8h bf1 = wsv[W1_OFF + 256 + t * 64 + lane];
            v4f c = __builtin_amdgcn_mfma_f32_16x16x32_f16(A0, bf0, (v4f)(0.0f), 0, 0, 0);
            c = __builtin_amdgcn_mfma_f32_16x16x32_f16(A1, bf1, c, 0, 0, 0);
            const int n = t * 16 + l15;
            const float bias = (n < 50) ? b1[n] : 0.0f;
            #pragma unroll
            for (int rg = 0; rg < 4; ++rg)
                seg[(q * 4 + rg) * 72 + n] = (_Float16)fast_tanh(c[rg] + bias);
        }
    }

    // ---- phase 3: proj = h2 @ [ww|wh|wd] + bias -> LDS col-major [c][row], stride 20 f16 ----
    {
        const v8h A0 = *(const v8h*)&seg[l15 * 72 + q * 8];
        const v8h A1 = *(const v8h*)&seg[l15 * 72 + 32 + q * 8];
        #pragma unroll 3
        for (int t = 0; t < 15; ++t) {
            const v8h bf0 = wsv[WC_OFF + t * 64 + lane];
            const v8h bf1 = wsv[WC_OFF + 960 + t * 64 + lane];
            v4f c = __builtin_amdgcn_mfma_f32_16x16x32_f16(A0, bf0, (v4f)(0.0f), 0, 0, 0);
            c = __builtin_amdgcn_mfma_f32_16x16x32_f16(A1, bf1, c, 0, 0, 0);
            const int cc = t * 16 + l15;
            if (cc < 232) {
                const float bias = cc < 80 ? bw[cc] : cc < 160 ? bh[cc - 80] : bd[cc - 160];
                v4h pk;
                #pragma unroll
                for (int rg = 0; rg < 4; ++rg) pk[rg] = (_Float16)(c[rg] + bias);
                *(v4h*)&seg[cc * PSTRIDE + q * 4] = pk;   // rows q*4..q*4+3, 8B-aligned b64
            }
        }
    }

    // ---- epilogue: 2 (row, dim) tasks per lane; proj read from wave-private LDS ----
    float ldacc = 0.0f;
    #pragma unroll
    for (int tt = 0; tt < 2; ++tt) {
        const int d = (lane >> 4) + tt * 4;   // 0..7
        const int row = l15;
        const int g = R0 + row;

        float aw[KK], ah[KK], ad9[KK - 1];
        #pragma unroll
        for (int i = 0; i < KK; ++i)     aw[i]  = (float)seg[(d * 10 + i) * PSTRIDE + row];
        #pragma unroll
        for (int i = 0; i < KK; ++i)     ah[i]  = (float)seg[(80 + d * 10 + i) * PSTRIDE + row];
        #pragma unroll
        for (int i = 0; i < KK - 1; ++i) ad9[i] = (float)seg[(160 + d * 9 + i) * PSTRIDE + row];

        // softmax over K for widths (logits = 6*aw)
        float mw = aw[0];
        #pragma unroll
        for (int i = 1; i < KK; ++i) mw = fmaxf(mw, aw[i]);
        float sw = 0.0f;
        #pragma unroll
        for (int i = 0; i < KK; ++i) { aw[i] = __expf(6.0f * (aw[i] - mw)); sw += aw[i]; }
        const float invw = __fdividef(1.0f, sw);

        float mh = ah[0];
        #pragma unroll
        for (int i = 1; i < KK; ++i) mh = fmaxf(mh, ah[i]);
        float sh = 0.0f;
        #pragma unroll
        for (int i = 0; i < KK; ++i) { ah[i] = __expf(6.0f * (ah[i] - mh)); sh += ah[i]; }
        const float invh = __fdividef(1.0f, sh);

        float sp[KK - 1];
        #pragma unroll
        for (int i = 0; i < KK - 1; ++i) {
            const float v = ad9[i];
            sp[i] = fmaxf(v, 0.0f) + __logf(1.0f + __expf(-fabsf(v)));
        }

        const float ud = x[g * 16 + 8 + d];   // fp32 u (exact passthrough outside bounds)
        const float uc = fminf(fmaxf(ud, -BB), BB);
        const bool inside = (ud > -BB) && (ud < BB);

        // streaming bin search + parameter select
        float cw = 0.0f, ch = 0.0f;
        float xprev = -BB, yprev = -BB, dprev = 1.0f;
        float xk = -BB, yk = -BB, wk = 1.0f, hk2 = 1.0f, dk = 1.0f, dk1 = 1.0f;
        #pragma unroll
        for (int i = 0; i < KK; ++i) {
            cw += aw[i] * invw;
            ch += ah[i] * invh;
            const float xnext = fmaf(6.0f, cw, -BB);
            const float ynext = fmaf(6.0f, ch, -BB);
            const float dnext = (i == KK - 1) ? 1.0f : sp[i];
            const bool c = (i == 0) || (uc >= xprev);
            if (c) { xk = xprev; yk = yprev; wk = xnext - xprev; hk2 = ynext - yprev; dk = dprev; dk1 = dnext; }
            xprev = xnext; yprev = ynext; dprev = dnext;
        }

        const float sk = __fdividef(hk2, wk);
        const float xi = __fdividef(uc - xk, wk);
        const float om = 1.0f - xi;
        const float denom = sk + (dk1 + dk - 2.0f * sk) * xi * om;
        const float ynum = sk * xi * xi + dk * xi * om;
        const float yv = yk + hk2 * __fdividef(ynum, denom);
        const float larg = dk1 * xi * xi + 2.0f * sk * xi * om + dk * om * om;
        const float ldet = 2.0f * __logf(sk) + __logf(larg) - 2.0f * __logf(denom);

        out[g * 16 + 8 + d] = inside ? yv : ud;
        ldacc += inside ? ldet : 0.0f;
    }

    // ---- logdet: wave shuffle-reduce -> slot-spread atomics (64 slots) ----
    #pragma unroll
    for (int off = 32; off > 0; off >>= 1) ldacc += __shfl_down(ldacc, off);
    if (lane == 0) atomicAdd(&slots[(blockIdx.x * 4 + wave) & 63], ldacc);
}

// ---- finish: sum the 64 partial slots into the scalar logdet output ----
__global__ void nsf_finish(const float* __restrict__ slots, float* __restrict__ ldp) {
    float v = slots[threadIdx.x];
    #pragma unroll
    for (int off = 32; off > 0; off >>= 1) v += __shfl_down(v, off);
    if (threadIdx.x == 0) *ldp = v;
}

extern "C" void kernel_launch(void* const* d_in, const int* in_sizes, int n_in,
                              void* d_out, int out_size, void* d_ws, size_t ws_size,
                              hipStream_t stream) {
    const float* x  = (const float*)d_in[0];
    const float* w0 = (const float*)d_in[1];
    const float* b0 = (const float*)d_in[2];
    const float* w1 = (const float*)d_in[3];
    const float* b1 = (const float*)d_in[4];
    const float* ww = (const float*)d_in[5];
    const float* bw = (const float*)d_in[6];
    const float* wh = (const float*)d_in[7];
    const float* bh = (const float*)d_in[8];
    const float* wd = (const float*)d_in[9];
    const float* bd = (const float*)d_in[10];

    float* out = (float*)d_out;
    float* ldp = out + (size_t)NROWS * 16;              // scalar logdet sum slot
    v8h* wsv = (v8h*)d_ws;                              // 43 KB packed B-fragments
    float* slots = (float*)((char*)d_ws + FRAG_TOTAL * 16);  // 64 partial sums

    hipLaunchKernelGGL(nsf_prep, dim3((FRAG_TOTAL + 255) / 256), dim3(256), 0, stream,
                       w0, w1, ww, wh, wd, wsv, slots);
    hipLaunchKernelGGL(nsf_main, dim3(NROWS / 64), dim3(256), 0, stream,
                       x, b0, b1, bw, bh, bd, wsv, out, slots);
    hipLaunchKernelGGL(nsf_finish, dim3(1), dim3(64), 0, stream, slots, ldp);
}

// Round 7
// 209.274 us; speedup vs baseline: 2.5834x; 1.0039x over previous
//
#include <hip/hip_runtime.h>

#define NROWS 262144
#define KK 10
#define BB 3.0f
#define PSTRIDE 16                 // f16 units per proj column; 16 rows exactly
#define SEGF16 (232 * PSTRIDE)     // 3712 f16 = 7424 B per wave-private LDS segment

typedef _Float16 v8h __attribute__((ext_vector_type(8)));
typedef _Float16 v4h __attribute__((ext_vector_type(4)));
typedef float v4f __attribute__((ext_vector_type(4)));

// d_ws layout: v8h frags: W0[256] | W1[512] | WC[1920] ; then f32: slots[64] | bcomb[232] | b0p[64] | b1p[64]
#define W0_OFF 0
#define W1_OFF 256
#define WC_OFF 768
#define FRAG_TOTAL 2688
#define SLOTS_OFF (FRAG_TOTAL * 8)       // in f32 units from ws base
#define BCOMB_OFF (SLOTS_OFF + 64)
#define B0P_OFF   (BCOMB_OFF + 232)
#define B1P_OFF   (B0P_OFF + 64)

__device__ __forceinline__ float fast_tanh(float a) {
    float e = __expf(2.0f * a);
    return 1.0f - __fdividef(2.0f, e + 1.0f);
}

// ---- prep: pack B-fragments + bias tables; zero logdet slots ----
__global__ __launch_bounds__(256) void nsf_prep(
    const float* __restrict__ w0, const float* __restrict__ b0,
    const float* __restrict__ w1, const float* __restrict__ b1,
    const float* __restrict__ ww, const float* __restrict__ bw,
    const float* __restrict__ wh, const float* __restrict__ bh,
    const float* __restrict__ wd, const float* __restrict__ bd,
    v8h* __restrict__ wsv, float* __restrict__ wsf)
{
    const int t = blockIdx.x * 256 + threadIdx.x;
    if (t < 64)  wsf[SLOTS_OFF + t] = 0.0f;
    if (t < 232) wsf[BCOMB_OFF + t] = t < 80 ? bw[t] : t < 160 ? bh[t - 80] : bd[t - 160];
    if (t < 64)  wsf[B0P_OFF + t] = (t < 50) ? b0[t] : 0.0f;
    if (t < 64)  wsf[B1P_OFF + t] = (t < 50) ? b1[t] : 0.0f;
    if (t >= FRAG_TOTAL) return;

    v8h v;
    #pragma unroll
    for (int j = 0; j < 8; ++j) v[j] = (_Float16)0.0f;

    if (t < W1_OFF) {                       // W0: 8x50 padded to K=32, 4 col tiles
        const int tile = t >> 6, lane = t & 63, q = lane >> 4, n = tile * 16 + (lane & 15);
        #pragma unroll
        for (int j = 0; j < 8; ++j) {
            const int k = q * 8 + j;
            if (k < 8 && n < 50) v[j] = (_Float16)w0[k * 50 + n];
        }
    } else if (t < WC_OFF) {                // W1: 50x50, 2 k-steps, 4 col tiles
        int p = t - W1_OFF;
        const int step = p >> 8; p &= 255;
        const int tile = p >> 6, lane = p & 63, q = lane >> 4, n = tile * 16 + (lane & 15);
        #pragma unroll
        for (int j = 0; j < 8; ++j) {
            const int k = step * 32 + q * 8 + j;
            if (k < 50 && n < 50) v[j] = (_Float16)w1[k * 50 + n];
        }
    } else {                                // WC = [ww|wh|wd]: 50x232, 2 k-steps, 15 col tiles
        int p = t - WC_OFF;
        const int step = p / 960; p -= step * 960;
        const int tile = p >> 6, lane = p & 63, q = lane >> 4, c = tile * 16 + (lane & 15);
        #pragma unroll
        for (int j = 0; j < 8; ++j) {
            const int k = step * 32 + q * 8 + j;
            if (k < 50 && c < 232)
                v[j] = (_Float16)(c < 80 ? ww[k * 80 + c]
                                : c < 160 ? wh[k * 80 + (c - 80)]
                                          : wd[k * 72 + (c - 160)]);
        }
    }
    wsv[t] = v;
}

// ---- main: 2 waves/block, 1 wave = 16 rows; MFMA; wave-private LDS; no __syncthreads ----
__global__ __launch_bounds__(128, 6) void nsf_main(
    const float* __restrict__ x,
    const v8h* __restrict__ wsv, const float* __restrict__ wsf,
    float* __restrict__ out, float* __restrict__ slots)
{
    __shared__ __align__(16) _Float16 smem[2 * SEGF16];   // 14848 B -> 11 blocks/CU
    const int tid = threadIdx.x, wave = tid >> 6, lane = tid & 63;
    const int q = lane >> 4, l15 = lane & 15;
    _Float16* seg = &smem[wave * SEGF16];
    const int R0 = blockIdx.x * 32 + wave * 16;           // first row of this wave's tile

    const float4* xv = (const float4*)x;
    float4* ov = (float4*)out;

    // prefetch epilogue u values early (hide global latency behind the matmul phases)
    const float u_t0 = x[(R0 + l15) * 16 + 8 + q];
    const float u_t1 = x[(R0 + l15) * 16 + 12 + q];

    // passthrough of the 8 scale dims (lanes 0..31: 2 float4 per row)
    if (lane < 32) {
        const int g = R0 + (lane >> 1);
        const int part = lane & 1;
        ov[g * 4 + part] = xv[g * 4 + part];
    }

    // ---- phase 0: zd A-fragment (k<8 real, rest zero) ----
    v8h a;
    #pragma unroll
    for (int j = 0; j < 8; ++j) a[j] = (_Float16)0.0f;
    if (lane < 16) {   // q==0, m=lane
        const int g = R0 + lane;
        const float4 f0 = xv[g * 4 + 0];
        const float4 f1 = xv[g * 4 + 1];
        a[0] = (_Float16)f0.x; a[1] = (_Float16)f0.y; a[2] = (_Float16)f0.z; a[3] = (_Float16)f0.w;
        a[4] = (_Float16)f1.x; a[5] = (_Float16)f1.y; a[6] = (_Float16)f1.z; a[7] = (_Float16)f1.w;
    }

    // ---- phase 1: h1 = tanh(zd @ w0 + b0) -> LDS row-major [m][k], stride 72 f16 ----
    #pragma unroll
    for (int t = 0; t < 4; ++t) {
        const v8h b = wsv[W0_OFF + t * 64 + lane];
        v4f c = __builtin_amdgcn_mfma_f32_16x16x32_f16(a, b, (v4f)(0.0f), 0, 0, 0);
        const int n = t * 16 + l15;
        const float bias = wsf[B0P_OFF + n];
        #pragma unroll
        for (int rg = 0; rg < 4; ++rg)
            seg[(q * 4 + rg) * 72 + n] = (_Float16)fast_tanh(c[rg] + bias);
    }

    // ---- phase 2: h2 = tanh(h1 @ w1 + b1) ----
    {
        const v8h A0 = *(const v8h*)&seg[l15 * 72 + q * 8];        // k = q*8+j
        const v8h A1 = *(const v8h*)&seg[l15 * 72 + 32 + q * 8];   // k = 32+q*8+j
        #pragma unroll
        for (int t = 0; t < 4; ++t) {
            const v8h bf0 = wsv[W1_OFF + t * 64 + lane];
            const v8h bf1 = wsv[W1_OFF + 256 + t * 64 + lane];
            v4f c = __builtin_amdgcn_mfma_f32_16x16x32_f16(A0, bf0, (v4f)(0.0f), 0, 0, 0);
            c = __builtin_amdgcn_mfma_f32_16x16x32_f16(A1, bf1, c, 0, 0, 0);
            const int n = t * 16 + l15;
            const float bias = wsf[B1P_OFF + n];
            #pragma unroll
            for (int rg = 0; rg < 4; ++rg)
                seg[(q * 4 + rg) * 72 + n] = (_Float16)fast_tanh(c[rg] + bias);
        }
    }

    // ---- phase 3: proj = h2 @ [ww|wh|wd] + bias -> LDS col-major [c][row], stride 16 f16 ----
    {
        const v8h A0 = *(const v8h*)&seg[l15 * 72 + q * 8];
        const v8h A1 = *(const v8h*)&seg[l15 * 72 + 32 + q * 8];
        #pragma unroll 5
        for (int t = 0; t < 15; ++t) {
            const v8h bf0 = wsv[WC_OFF + t * 64 + lane];
            const v8h bf1 = wsv[WC_OFF + 960 + t * 64 + lane];
            v4f c = __builtin_amdgcn_mfma_f32_16x16x32_f16(A0, bf0, (v4f)(0.0f), 0, 0, 0);
            c = __builtin_amdgcn_mfma_f32_16x16x32_f16(A1, bf1, c, 0, 0, 0);
            const int cc = t * 16 + l15;
            if (cc < 232) {
                const float bias = wsf[BCOMB_OFF + cc];
                v4h pk;
                #pragma unroll
                for (int rg = 0; rg < 4; ++rg) pk[rg] = (_Float16)(c[rg] + bias);
                *(v4h*)&seg[cc * PSTRIDE + q * 4] = pk;   // rows q*4..q*4+3, 8B-aligned b64
            }
        }
    }

    // ---- epilogue: 2 (row, dim) tasks per lane; proj read from wave-private LDS ----
    float ldacc = 0.0f;
    #pragma unroll
    for (int tt = 0; tt < 2; ++tt) {
        const int d = q + tt * 4;             // 0..7
        const int row = l15;
        const int g = R0 + row;
        const float ud = tt == 0 ? u_t0 : u_t1;

        float aw[KK], ah[KK], ad9[KK - 1];
        #pragma unroll
        for (int i = 0; i < KK; ++i)     aw[i]  = (float)seg[(d * 10 + i) * PSTRIDE + row];
        #pragma unroll
        for (int i = 0; i < KK; ++i)     ah[i]  = (float)seg[(80 + d * 10 + i) * PSTRIDE + row];
        #pragma unroll
        for (int i = 0; i < KK - 1; ++i) ad9[i] = (float)seg[(160 + d * 9 + i) * PSTRIDE + row];

        // softmax over K for widths (logits = 6*aw)
        float mw = aw[0];
        #pragma unroll
        for (int i = 1; i < KK; ++i) mw = fmaxf(mw, aw[i]);
        float sw = 0.0f;
        #pragma unroll
        for (int i = 0; i < KK; ++i) { aw[i] = __expf(6.0f * (aw[i] - mw)); sw += aw[i]; }
        const float invw = __fdividef(1.0f, sw);

        float mh = ah[0];
        #pragma unroll
        for (int i = 1; i < KK; ++i) mh = fmaxf(mh, ah[i]);
        float sh = 0.0f;
        #pragma unroll
        for (int i = 0; i < KK; ++i) { ah[i] = __expf(6.0f * (ah[i] - mh)); sh += ah[i]; }
        const float invh = __fdividef(1.0f, sh);

        float sp[KK - 1];
        #pragma unroll
        for (int i = 0; i < KK - 1; ++i) {
            const float v = ad9[i];
            sp[i] = fmaxf(v, 0.0f) + __logf(1.0f + __expf(-fabsf(v)));
        }

        const float uc = fminf(fmaxf(ud, -BB), BB);
        const bool inside = (ud > -BB) && (ud < BB);

        // streaming bin search + parameter select
        float cw = 0.0f, ch = 0.0f;
        float xprev = -BB, yprev = -BB, dprev = 1.0f;
        float xk = -BB, yk = -BB, wk = 1.0f, hk2 = 1.0f, dk = 1.0f, dk1 = 1.0f;
        #pragma unroll
        for (int i = 0; i < KK; ++i) {
            cw += aw[i] * invw;
            ch += ah[i] * invh;
            const float xnext = fmaf(6.0f, cw, -BB);
            const float ynext = fmaf(6.0f, ch, -BB);
            const float dnext = (i == KK - 1) ? 1.0f : sp[i];
            const bool c = (i == 0) || (uc >= xprev);
            if (c) { xk = xprev; yk = yprev; wk = xnext - xprev; hk2 = ynext - yprev; dk = dprev; dk1 = dnext; }
            xprev = xnext; yprev = ynext; dprev = dnext;
        }

        const float sk = __fdividef(hk2, wk);
        const float xi = __fdividef(uc - xk, wk);
        const float om = 1.0f - xi;
        const float denom = sk + (dk1 + dk - 2.0f * sk) * xi * om;
        const float ynum = sk * xi * xi + dk * xi * om;
        const float yv = yk + hk2 * __fdividef(ynum, denom);
        const float larg = dk1 * xi * xi + 2.0f * sk * xi * om + dk * om * om;
        const float ldet = 2.0f * __logf(sk) + __logf(larg) - 2.0f * __logf(denom);

        out[g * 16 + 8 + d] = inside ? yv : ud;
        ldacc += inside ? ldet : 0.0f;
    }

    // ---- logdet: wave shuffle-reduce -> slot-spread atomics (64 slots) ----
    #pragma unroll
    for (int off = 32; off > 0; off >>= 1) ldacc += __shfl_down(ldacc, off);
    if (lane == 0) atomicAdd(&slots[(blockIdx.x * 2 + wave) & 63], ldacc);
}

// ---- finish: sum the 64 partial slots into the scalar logdet output ----
__global__ void nsf_finish(const float* __restrict__ slots, float* __restrict__ ldp) {
    float v = slots[threadIdx.x];
    #pragma unroll
    for (int off = 32; off > 0; off >>= 1) v += __shfl_down(v, off);
    if (threadIdx.x == 0) *ldp = v;
}

extern "C" void kernel_launch(void* const* d_in, const int* in_sizes, int n_in,
                              void* d_out, int out_size, void* d_ws, size_t ws_size,
                              hipStream_t stream) {
    const float* x  = (const float*)d_in[0];
    const float* w0 = (const float*)d_in[1];
    const float* b0 = (const float*)d_in[2];
    const float* w1 = (const float*)d_in[3];
    const float* b1 = (const float*)d_in[4];
    const float* ww = (const float*)d_in[5];
    const float* bw = (const float*)d_in[6];
    const float* wh = (const float*)d_in[7];
    const float* bh = (const float*)d_in[8];
    const float* wd = (const float*)d_in[9];
    const float* bd = (const float*)d_in[10];

    float* out = (float*)d_out;
    float* ldp = out + (size_t)NROWS * 16;   // scalar logdet sum slot
    v8h* wsv = (v8h*)d_ws;                   // 43 KB packed B-fragments
    float* wsf = (float*)d_ws;               // f32 view (slots/bias tables)
    float* slots = wsf + SLOTS_OFF;

    hipLaunchKernelGGL(nsf_prep, dim3((FRAG_TOTAL + 255) / 256), dim3(256), 0, stream,
                       w0, b0, w1, b1, ww, bw, wh, bh, wd, bd, wsv, wsf);
    hipLaunchKernelGGL(nsf_main, dim3(NROWS / 32), dim3(128), 0, stream,
                       x, wsv, wsf, out, slots);
    hipLaunchKernelGGL(nsf_finish, dim3(1), dim3(64), 0, stream, slots, ldp);
}

// Round 8
// 206.101 us; speedup vs baseline: 2.6232x; 1.0154x over previous
//
#include <hip/hip_runtime.h>

#define NROWS 262144
#define KK 10
#define BB 3.0f
#define SROW 260                   // f16 units per row region (8 slots of 32 + 4 pad)
#define SEGF16 (16 * SROW)         // 4160 f16 = 8320 B per wave-private LDS segment

typedef _Float16 v8h __attribute__((ext_vector_type(8)));
typedef _Float16 v4h __attribute__((ext_vector_type(4)));
typedef float v4f __attribute__((ext_vector_type(4)));

// d_ws layout: v8h frags: W0[4*64] | W1[2*4*64] | WC[2*16*64] ; then f32 slots[64]
#define W0_OFF 0
#define W1_OFF 256
#define WC_OFF 768
#define FRAG_TOTAL 2816
#define SLOTS_OFF (FRAG_TOTAL * 4)   // f32 units from ws base (FRAG_TOTAL*16 bytes)

__device__ __forceinline__ float fast_tanh(float a) {
    float e = __expf(2.0f * a);
    return 1.0f - __fdividef(2.0f, e + 1.0f);
}

// ---- prep: pack B-fragments with bias folded into k=8/k=50 row; zero logdet slots ----
// B-frag layout per m89: lane holds B[k=quad*8+j][n=lane&15] for j=0..7.
__global__ __launch_bounds__(256) void nsf_prep(
    const float* __restrict__ w0, const float* __restrict__ b0,
    const float* __restrict__ w1, const float* __restrict__ b1,
    const float* __restrict__ ww, const float* __restrict__ bw,
    const float* __restrict__ wh, const float* __restrict__ bh,
    const float* __restrict__ wd, const float* __restrict__ bd,
    v8h* __restrict__ wsv, float* __restrict__ wsf)
{
    const int t = blockIdx.x * 256 + threadIdx.x;
    if (t < 64) wsf[SLOTS_OFF + t] = 0.0f;
    if (t >= FRAG_TOTAL) return;

    v8h v;
    #pragma unroll
    for (int j = 0; j < 8; ++j) v[j] = (_Float16)0.0f;

    if (t < W1_OFF) {                       // W0: 9x50 (row 8 = b0) padded to K=32, 4 col tiles
        const int tile = t >> 6, lane = t & 63, q = lane >> 4, n = tile * 16 + (lane & 15);
        if (n < 50) {
            #pragma unroll
            for (int j = 0; j < 8; ++j) {
                const int k = q * 8 + j;
                if (k < 8)       v[j] = (_Float16)w0[k * 50 + n];
                else if (k == 8) v[j] = (_Float16)b0[n];
            }
        }
    } else if (t < WC_OFF) {                // W1: 51x50 (row 50 = b1), 2 k-steps, 4 col tiles
        int p = t - W1_OFF;
        const int step = p >> 8; p &= 255;
        const int tile = p >> 6, lane = p & 63, q = lane >> 4, n = tile * 16 + (lane & 15);
        if (n < 50) {
            #pragma unroll
            for (int j = 0; j < 8; ++j) {
                const int k = step * 32 + q * 8 + j;
                if (k < 50)       v[j] = (_Float16)w1[k * 50 + n];
                else if (k == 50) v[j] = (_Float16)b1[n];
            }
        }
    } else {                                // WC: 51x256 (row 50 = bias), cols c' = d*32 + jj
        int p = t - WC_OFF;
        const int step = p >> 10; p &= 1023;
        const int tile = p >> 6, lane = p & 63, q = lane >> 4;
        const int cp = tile * 16 + (lane & 15);
        const int d = cp >> 5, jj = cp & 31;
        #pragma unroll
        for (int j = 0; j < 8; ++j) {
            const int k = step * 32 + q * 8 + j;
            float val = 0.0f;
            if (k < 50) {
                if (jj < 10)      val = ww[k * 80 + d * 10 + jj];
                else if (jj < 20) val = wh[k * 80 + d * 10 + (jj - 10)];
                else if (jj < 29) val = wd[k * 72 + d * 9 + (jj - 20)];
            } else if (k == 50) {
                if (jj < 10)      val = bw[d * 10 + jj];
                else if (jj < 20) val = bh[d * 10 + (jj - 10)];
                else if (jj < 29) val = bd[d * 9 + (jj - 20)];
            }
            v[j] = (_Float16)val;
        }
    }
    wsv[t] = v;
}

// ---- main: 2 waves/block, 1 wave = 16 rows; MFMA; wave-private LDS; no __syncthreads ----
__global__ __launch_bounds__(128, 4) void nsf_main(
    const float* __restrict__ x,
    const v8h* __restrict__ wsv,
    float* __restrict__ out, float* __restrict__ slots)
{
    __shared__ __align__(16) _Float16 smem[2 * SEGF16];   // 16640 B -> 9 blocks/CU
    const int tid = threadIdx.x, wave = tid >> 6, lane = tid & 63;
    const int q = lane >> 4, l15 = lane & 15;
    _Float16* seg = &smem[wave * SEGF16];
    const int R0 = blockIdx.x * 32 + wave * 16;           // first row of this wave's tile

    const float4* xv = (const float4*)x;
    float4* ov = (float4*)out;

    // prefetch epilogue u values early (hide global latency behind the matmul phases)
    const float u_t0 = x[(R0 + l15) * 16 + 8 + q];
    const float u_t1 = x[(R0 + l15) * 16 + 12 + q];

    // passthrough of the 8 scale dims (lanes 0..31: 2 float4 per row)
    if (lane < 32) {
        const int g = R0 + (lane >> 1);
        const int part = lane & 1;
        ov[g * 4 + part] = xv[g * 4 + part];
    }

    // ---- phase 0: zd A-fragment (k<8 real, k=8 -> 1.0 for bias row) ----
    v8h a;
    #pragma unroll
    for (int j = 0; j < 8; ++j) a[j] = (_Float16)0.0f;
    if (lane < 16) {   // q==0, m=lane
        const int g = R0 + lane;
        const float4 f0 = xv[g * 4 + 0];
        const float4 f1 = xv[g * 4 + 1];
        a[0] = (_Float16)f0.x; a[1] = (_Float16)f0.y; a[2] = (_Float16)f0.z; a[3] = (_Float16)f0.w;
        a[4] = (_Float16)f1.x; a[5] = (_Float16)f1.y; a[6] = (_Float16)f1.z; a[7] = (_Float16)f1.w;
    }
    if (q == 1) a[0] = (_Float16)1.0f;      // k = 8: bias row

    // ---- phase 1: h1 = tanh(zd @ [w0;b0]) -> LDS row-major [m][k], stride 72 f16 ----
    #pragma unroll
    for (int t = 0; t < 4; ++t) {
        const v8h b = wsv[W0_OFF + t * 64 + lane];
        v4f c = __builtin_amdgcn_mfma_f32_16x16x32_f16(a, b, (v4f)(0.0f), 0, 0, 0);
        const int n = t * 16 + l15;
        #pragma unroll
        for (int rg = 0; rg < 4; ++rg)
            seg[(q * 4 + rg) * 72 + n] = (_Float16)fast_tanh(c[rg]);
    }

    // ---- phase 2: h2 = tanh(h1 @ [w1;b1]) ----
    {
        v8h A0 = *(const v8h*)&seg[l15 * 72 + q * 8];        // k = q*8+j
        v8h A1 = *(const v8h*)&seg[l15 * 72 + 32 + q * 8];   // k = 32+q*8+j
        if (q == 2) A1[2] = (_Float16)1.0f;                  // k = 50: bias row
        #pragma unroll
        for (int t = 0; t < 4; ++t) {
            const v8h bf0 = wsv[W1_OFF + t * 64 + lane];
            const v8h bf1 = wsv[W1_OFF + 256 + t * 64 + lane];
            v4f c = __builtin_amdgcn_mfma_f32_16x16x32_f16(A0, bf0, (v4f)(0.0f), 0, 0, 0);
            c = __builtin_amdgcn_mfma_f32_16x16x32_f16(A1, bf1, c, 0, 0, 0);
            const int n = t * 16 + l15;
            #pragma unroll
            for (int rg = 0; rg < 4; ++rg)
                seg[(q * 4 + rg) * 72 + n] = (_Float16)fast_tanh(c[rg]);
        }
    }

    // ---- phase 3: proj -> LDS slots seg[row*260 + c'], c' = d*32 + j ----
    {
        v8h A0 = *(const v8h*)&seg[l15 * 72 + q * 8];
        v8h A1 = *(const v8h*)&seg[l15 * 72 + 32 + q * 8];
        if (q == 2) A1[2] = (_Float16)1.0f;                  // k = 50: bias row
        #pragma unroll 4
        for (int t = 0; t < 16; ++t) {
            const v8h bf0 = wsv[WC_OFF + t * 64 + lane];
            const v8h bf1 = wsv[WC_OFF + 1024 + t * 64 + lane];
            v4f c = __builtin_amdgcn_mfma_f32_16x16x32_f16(A0, bf0, (v4f)(0.0f), 0, 0, 0);
            c = __builtin_amdgcn_mfma_f32_16x16x32_f16(A1, bf1, c, 0, 0, 0);
            const int cp = t * 16 + l15;
            #pragma unroll
            for (int rg = 0; rg < 4; ++rg)
                seg[(q * 4 + rg) * SROW + cp] = (_Float16)c[rg];
        }
    }

    // ---- epilogue: 2 (row, dim) tasks per lane, rolled; 8 x ds_read_b64 per task ----
    float ldacc = 0.0f;
    #pragma unroll 1
    for (int tt = 0; tt < 2; ++tt) {
        const int d = q + tt * 4;             // 0..7
        const int g = R0 + l15;
        const float ud = (tt == 0) ? u_t0 : u_t1;
        const int base = l15 * SROW + d * 32;

        float vals[32];
        #pragma unroll
        for (int blk = 0; blk < 8; ++blk) {
            const v4h p = *(const v4h*)&seg[base + blk * 4];
            vals[4 * blk + 0] = (float)p[0];
            vals[4 * blk + 1] = (float)p[1];
            vals[4 * blk + 2] = (float)p[2];
            vals[4 * blk + 3] = (float)p[3];
        }
        // vals[0..9]=aw logits, [10..19]=ah logits, [20..28]=ad raw

        // softmax over K for widths (logits = 6*aw)
        float mw = vals[0];
        #pragma unroll
        for (int i = 1; i < KK; ++i) mw = fmaxf(mw, vals[i]);
        float sw = 0.0f;
        #pragma unroll
        for (int i = 0; i < KK; ++i) { vals[i] = __expf(6.0f * (vals[i] - mw)); sw += vals[i]; }
        const float invw = __fdividef(1.0f, sw);

        float mh = vals[10];
        #pragma unroll
        for (int i = 1; i < KK; ++i) mh = fmaxf(mh, vals[10 + i]);
        float sh = 0.0f;
        #pragma unroll
        for (int i = 0; i < KK; ++i) { vals[10 + i] = __expf(6.0f * (vals[10 + i] - mh)); sh += vals[10 + i]; }
        const float invh = __fdividef(1.0f, sh);

        float sp[KK - 1];
        #pragma unroll
        for (int i = 0; i < KK - 1; ++i) {
            const float v = vals[20 + i];
            sp[i] = fmaxf(v, 0.0f) + __logf(1.0f + __expf(-fabsf(v)));
        }

        const float uc = fminf(fmaxf(ud, -BB), BB);
        const bool inside = (ud > -BB) && (ud < BB);

        // streaming bin search + parameter select
        float cw = 0.0f, ch = 0.0f;
        float xprev = -BB, yprev = -BB, dprev = 1.0f;
        float xk = -BB, yk = -BB, wk = 1.0f, hk2 = 1.0f, dk = 1.0f, dk1 = 1.0f;
        #pragma unroll
        for (int i = 0; i < KK; ++i) {
            cw += vals[i] * invw;
            ch += vals[10 + i] * invh;
            const float xnext = fmaf(6.0f, cw, -BB);
            const float ynext = fmaf(6.0f, ch, -BB);
            const float dnext = (i == KK - 1) ? 1.0f : sp[i];
            const bool c = (i == 0) || (uc >= xprev);
            if (c) { xk = xprev; yk = yprev; wk = xnext - xprev; hk2 = ynext - yprev; dk = dprev; dk1 = dnext; }
            xprev = xnext; yprev = ynext; dprev = dnext;
        }

        const float sk = __fdividef(hk2, wk);
        const float xi = __fdividef(uc - xk, wk);
        const float om = 1.0f - xi;
        const float denom = sk + (dk1 + dk - 2.0f * sk) * xi * om;
        const float ynum = sk * xi * xi + dk * xi * om;
        const float yv = yk + hk2 * __fdividef(ynum, denom);
        const float larg = dk1 * xi * xi + 2.0f * sk * xi * om + dk * om * om;
        const float ldet = 2.0f * __logf(sk) + __logf(larg) - 2.0f * __logf(denom);

        out[g * 16 + 8 + d] = inside ? yv : ud;
        ldacc += inside ? ldet : 0.0f;
    }

    // ---- logdet: wave shuffle-reduce -> slot-spread atomics (64 slots) ----
    #pragma unroll
    for (int off = 32; off > 0; off >>= 1) ldacc += __shfl_down(ldacc, off);
    if (lane == 0) atomicAdd(&slots[(blockIdx.x * 2 + wave) & 63], ldacc);
}

// ---- finish: sum the 64 partial slots into the scalar logdet output ----
__global__ void nsf_finish(const float* __restrict__ slots, float* __restrict__ ldp) {
    float v = slots[threadIdx.x];
    #pragma unroll
    for (int off = 32; off > 0; off >>= 1) v += __shfl_down(v, off);
    if (threadIdx.x == 0) *ldp = v;
}

extern "C" void kernel_launch(void* const* d_in, const int* in_sizes, int n_in,
                              void* d_out, int out_size, void* d_ws, size_t ws_size,
                              hipStream_t stream) {
    const float* x  = (const float*)d_in[0];
    const float* w0 = (const float*)d_in[1];
    const float* b0 = (const float*)d_in[2];
    const float* w1 = (const float*)d_in[3];
    const float* b1 = (const float*)d_in[4];
    const float* ww = (const float*)d_in[5];
    const float* bw = (const float*)d_in[6];
    const float* wh = (const float*)d_in[7];
    const float* bh = (const float*)d_in[8];
    const float* wd = (const float*)d_in[9];
    const float* bd = (const float*)d_in[10];

    float* out = (float*)d_out;
    float* ldp = out + (size_t)NROWS * 16;   // scalar logdet sum slot
    v8h* wsv = (v8h*)d_ws;                   // 45 KB packed B-fragments (bias folded)
    float* wsf = (float*)d_ws;               // f32 view for slots
    float* slots = wsf + SLOTS_OFF;

    hipLaunchKernelGGL(nsf_prep, dim3((FRAG_TOTAL + 255) / 256), dim3(256), 0, stream,
                       w0, b0, w1, b1, ww, bw, wh, bh, wd, bd, wsv, wsf);
    hipLaunchKernelGGL(nsf_main, dim3(NROWS / 32), dim3(128), 0, stream,
                       x, wsv, out, slots);
    hipLaunchKernelGGL(nsf_finish, dim3(1), dim3(64), 0, stream, slots, ldp);
}

// Round 9
// 169.710 us; speedup vs baseline: 3.1856x; 1.2144x over previous
//
#include <hip/hip_runtime.h>

#define NROWS 262144
#define KK 10
#define BB 3.0f
#define SROW 260                   // f16 units per row region (8 slots of 32 + 4 pad)
#define SEGF16 (16 * SROW)         // 4160 f16 = 8320 B per tile segment

typedef _Float16 v8h __attribute__((ext_vector_type(8)));
typedef _Float16 v4h __attribute__((ext_vector_type(4)));
typedef float v4f __attribute__((ext_vector_type(4)));

// d_ws layout: v8h frags: W0[4*64] | W1[2*4*64] | WC[2*16*64] ; then f32 slots[64]
#define W0_OFF 0
#define W1_OFF 256
#define WC_OFF 768
#define FRAG_TOTAL 2816
#define SLOTS_OFF (FRAG_TOTAL * 4)   // f32 units from ws base (FRAG_TOTAL*16 bytes)

__device__ __forceinline__ float fast_tanh(float a) {
    float e = __expf(2.0f * a);
    return 1.0f - __fdividef(2.0f, e + 1.0f);
}

// ---- prep: pack B-fragments with bias folded into k=8/k=50 row; zero logdet slots ----
__global__ __launch_bounds__(256) void nsf_prep(
    const float* __restrict__ w0, const float* __restrict__ b0,
    const float* __restrict__ w1, const float* __restrict__ b1,
    const float* __restrict__ ww, const float* __restrict__ bw,
    const float* __restrict__ wh, const float* __restrict__ bh,
    const float* __restrict__ wd, const float* __restrict__ bd,
    v8h* __restrict__ wsv, float* __restrict__ wsf)
{
    const int t = blockIdx.x * 256 + threadIdx.x;
    if (t < 64) wsf[SLOTS_OFF + t] = 0.0f;
    if (t >= FRAG_TOTAL) return;

    v8h v;
    #pragma unroll
    for (int j = 0; j < 8; ++j) v[j] = (_Float16)0.0f;

    if (t < W1_OFF) {                       // W0: 9x50 (row 8 = b0) padded to K=32, 4 col tiles
        const int tile = t >> 6, lane = t & 63, q = lane >> 4, n = tile * 16 + (lane & 15);
        if (n < 50) {
            #pragma unroll
            for (int j = 0; j < 8; ++j) {
                const int k = q * 8 + j;
                if (k < 8)       v[j] = (_Float16)w0[k * 50 + n];
                else if (k == 8) v[j] = (_Float16)b0[n];
            }
        }
    } else if (t < WC_OFF) {                // W1: 51x50 (row 50 = b1), 2 k-steps, 4 col tiles
        int p = t - W1_OFF;
        const int step = p >> 8; p &= 255;
        const int tile = p >> 6, lane = p & 63, q = lane >> 4, n = tile * 16 + (lane & 15);
        if (n < 50) {
            #pragma unroll
            for (int j = 0; j < 8; ++j) {
                const int k = step * 32 + q * 8 + j;
                if (k < 50)       v[j] = (_Float16)w1[k * 50 + n];
                else if (k == 50) v[j] = (_Float16)b1[n];
            }
        }
    } else {                                // WC: 51x256 (row 50 = bias), cols c' = d*32 + jj
        int p = t - WC_OFF;
        const int step = p >> 10; p &= 1023;
        const int tile = p >> 6, lane = p & 63, q = lane >> 4;
        const int cp = tile * 16 + (lane & 15);
        const int d = cp >> 5, jj = cp & 31;
        #pragma unroll
        for (int j = 0; j < 8; ++j) {
            const int k = step * 32 + q * 8 + j;
            float val = 0.0f;
            if (k < 50) {
                if (jj < 10)      val = ww[k * 80 + d * 10 + jj];
                else if (jj < 20) val = wh[k * 80 + d * 10 + (jj - 10)];
                else if (jj < 29) val = wd[k * 72 + d * 9 + (jj - 20)];
            } else if (k == 50) {
                if (jj < 10)      val = bw[d * 10 + jj];
                else if (jj < 20) val = bh[d * 10 + (jj - 10)];
                else if (jj < 29) val = bd[d * 9 + (jj - 20)];
            }
            v[j] = (_Float16)val;
        }
    }
    wsv[t] = v;
}

// ---- main: 1 wave/block, 2 independent 16-row tiles/wave; B-frags loaded once, used twice ----
__global__ __launch_bounds__(64, 2) void nsf_main(
    const float* __restrict__ x,
    const v8h* __restrict__ wsv,
    float* __restrict__ out, float* __restrict__ slots)
{
    __shared__ __align__(16) _Float16 smem[2 * SEGF16];   // 16640 B -> 9 blocks/CU
    const int lane = threadIdx.x & 63;
    const int q = lane >> 4, l15 = lane & 15;
    _Float16* segA = &smem[0];
    _Float16* segB = &smem[SEGF16];
    const int R0 = blockIdx.x * 32;                       // tile A: R0.., tile B: R0+16..

    const float4* xv = (const float4*)x;
    float4* ov = (float4*)out;

    // prefetch epilogue u values (4 tasks) early
    const float uA0 = x[(R0 + l15) * 16 + 8 + q];
    const float uA1 = x[(R0 + l15) * 16 + 12 + q];
    const float uB0 = x[(R0 + 16 + l15) * 16 + 8 + q];
    const float uB1 = x[(R0 + 16 + l15) * 16 + 12 + q];

    // passthrough of the 8 scale dims: all 64 lanes cover 32 rows x 2 float4
    {
        const int gg = R0 + (lane >> 1);
        const int part = lane & 1;
        ov[gg * 4 + part] = xv[gg * 4 + part];
    }

    // ---- phase 0: zd A-fragments for both tiles (k<8 real, k=8 -> 1.0 bias row) ----
    v8h aA, aB;
    #pragma unroll
    for (int j = 0; j < 8; ++j) { aA[j] = (_Float16)0.0f; aB[j] = (_Float16)0.0f; }
    if (lane < 16) {
        const float4 f0 = xv[(R0 + lane) * 4 + 0];
        const float4 f1 = xv[(R0 + lane) * 4 + 1];
        aA[0] = (_Float16)f0.x; aA[1] = (_Float16)f0.y; aA[2] = (_Float16)f0.z; aA[3] = (_Float16)f0.w;
        aA[4] = (_Float16)f1.x; aA[5] = (_Float16)f1.y; aA[6] = (_Float16)f1.z; aA[7] = (_Float16)f1.w;
        const float4 g0 = xv[(R0 + 16 + lane) * 4 + 0];
        const float4 g1 = xv[(R0 + 16 + lane) * 4 + 1];
        aB[0] = (_Float16)g0.x; aB[1] = (_Float16)g0.y; aB[2] = (_Float16)g0.z; aB[3] = (_Float16)g0.w;
        aB[4] = (_Float16)g1.x; aB[5] = (_Float16)g1.y; aB[6] = (_Float16)g1.z; aB[7] = (_Float16)g1.w;
    }
    if (q == 1) { aA[0] = (_Float16)1.0f; aB[0] = (_Float16)1.0f; }   // k=8: bias row

    // ---- phase 1: h1 = tanh(zd @ [w0;b0]) -> seg row-major [m][k], stride 72 ----
    #pragma unroll
    for (int t = 0; t < 4; ++t) {
        const v8h b = wsv[W0_OFF + t * 64 + lane];
        v4f cA = __builtin_amdgcn_mfma_f32_16x16x32_f16(aA, b, (v4f)(0.0f), 0, 0, 0);
        v4f cB = __builtin_amdgcn_mfma_f32_16x16x32_f16(aB, b, (v4f)(0.0f), 0, 0, 0);
        const int n = t * 16 + l15;
        #pragma unroll
        for (int rg = 0; rg < 4; ++rg) {
            segA[(q * 4 + rg) * 72 + n] = (_Float16)fast_tanh(cA[rg]);
            segB[(q * 4 + rg) * 72 + n] = (_Float16)fast_tanh(cB[rg]);
        }
    }

    // ---- phase 2: h2 = tanh(h1 @ [w1;b1]) ----
    v8h A0A, A1A, A0B, A1B;
    {
        A0A = *(const v8h*)&segA[l15 * 72 + q * 8];
        A1A = *(const v8h*)&segA[l15 * 72 + 32 + q * 8];
        A0B = *(const v8h*)&segB[l15 * 72 + q * 8];
        A1B = *(const v8h*)&segB[l15 * 72 + 32 + q * 8];
        if (q == 2) { A1A[2] = (_Float16)1.0f; A1B[2] = (_Float16)1.0f; }   // k=50: bias row
        #pragma unroll
        for (int t = 0; t < 4; ++t) {
            const v8h bf0 = wsv[W1_OFF + t * 64 + lane];
            const v8h bf1 = wsv[W1_OFF + 256 + t * 64 + lane];
            v4f cA = __builtin_amdgcn_mfma_f32_16x16x32_f16(A0A, bf0, (v4f)(0.0f), 0, 0, 0);
            cA = __builtin_amdgcn_mfma_f32_16x16x32_f16(A1A, bf1, cA, 0, 0, 0);
            v4f cB = __builtin_amdgcn_mfma_f32_16x16x32_f16(A0B, bf0, (v4f)(0.0f), 0, 0, 0);
            cB = __builtin_amdgcn_mfma_f32_16x16x32_f16(A1B, bf1, cB, 0, 0, 0);
            const int n = t * 16 + l15;
            #pragma unroll
            for (int rg = 0; rg < 4; ++rg) {
                segA[(q * 4 + rg) * 72 + n] = (_Float16)fast_tanh(cA[rg]);
                segB[(q * 4 + rg) * 72 + n] = (_Float16)fast_tanh(cB[rg]);
            }
        }
    }

    // ---- phase 3: proj -> seg slots [row*260 + d*32 + j] ----
    {
        A0A = *(const v8h*)&segA[l15 * 72 + q * 8];
        A1A = *(const v8h*)&segA[l15 * 72 + 32 + q * 8];
        A0B = *(const v8h*)&segB[l15 * 72 + q * 8];
        A1B = *(const v8h*)&segB[l15 * 72 + 32 + q * 8];
        if (q == 2) { A1A[2] = (_Float16)1.0f; A1B[2] = (_Float16)1.0f; }   // k=50: bias row
        #pragma unroll 2
        for (int t = 0; t < 16; ++t) {
            const v8h bf0 = wsv[WC_OFF + t * 64 + lane];
            const v8h bf1 = wsv[WC_OFF + 1024 + t * 64 + lane];
            v4f cA = __builtin_amdgcn_mfma_f32_16x16x32_f16(A0A, bf0, (v4f)(0.0f), 0, 0, 0);
            cA = __builtin_amdgcn_mfma_f32_16x16x32_f16(A1A, bf1, cA, 0, 0, 0);
            v4f cB = __builtin_amdgcn_mfma_f32_16x16x32_f16(A0B, bf0, (v4f)(0.0f), 0, 0, 0);
            cB = __builtin_amdgcn_mfma_f32_16x16x32_f16(A1B, bf1, cB, 0, 0, 0);
            const int cp = t * 16 + l15;
            #pragma unroll
            for (int rg = 0; rg < 4; ++rg) {
                segA[(q * 4 + rg) * SROW + cp] = (_Float16)cA[rg];
                segB[(q * 4 + rg) * SROW + cp] = (_Float16)cB[rg];
            }
        }
    }

    // ---- epilogue: 4 (tile, row, dim) tasks per lane, rolled ----
    float ldacc = 0.0f;
    #pragma unroll 1
    for (int task = 0; task < 4; ++task) {
        const int tile = task >> 1, tt = task & 1;
        const int d = q + tt * 4;             // 0..7
        const int g = R0 + tile * 16 + l15;
        const float ud = (tile == 0) ? (tt == 0 ? uA0 : uA1) : (tt == 0 ? uB0 : uB1);
        const _Float16* sg = (tile == 0) ? segA : segB;
        const int base = l15 * SROW + d * 32;

        float vals[32];
        #pragma unroll
        for (int blk = 0; blk < 8; ++blk) {
            const v4h p = *(const v4h*)&sg[base + blk * 4];
            vals[4 * blk + 0] = (float)p[0];
            vals[4 * blk + 1] = (float)p[1];
            vals[4 * blk + 2] = (float)p[2];
            vals[4 * blk + 3] = (float)p[3];
        }
        // vals[0..9]=aw logits, [10..19]=ah logits, [20..28]=ad raw

        float mw = vals[0];
        #pragma unroll
        for (int i = 1; i < KK; ++i) mw = fmaxf(mw, vals[i]);
        float sw = 0.0f;
        #pragma unroll
        for (int i = 0; i < KK; ++i) { vals[i] = __expf(6.0f * (vals[i] - mw)); sw += vals[i]; }
        const float invw = __fdividef(1.0f, sw);

        float mh = vals[10];
        #pragma unroll
        for (int i = 1; i < KK; ++i) mh = fmaxf(mh, vals[10 + i]);
        float sh = 0.0f;
        #pragma unroll
        for (int i = 0; i < KK; ++i) { vals[10 + i] = __expf(6.0f * (vals[10 + i] - mh)); sh += vals[10 + i]; }
        const float invh = __fdividef(1.0f, sh);

        float sp[KK - 1];
        #pragma unroll
        for (int i = 0; i < KK - 1; ++i) {
            const float v = vals[20 + i];
            sp[i] = fmaxf(v, 0.0f) + __logf(1.0f + __expf(-fabsf(v)));
        }

        const float uc = fminf(fmaxf(ud, -BB), BB);
        const bool inside = (ud > -BB) && (ud < BB);

        float cw = 0.0f, ch = 0.0f;
        float xprev = -BB, yprev = -BB, dprev = 1.0f;
        float xk = -BB, yk = -BB, wk = 1.0f, hk2 = 1.0f, dk = 1.0f, dk1 = 1.0f;
        #pragma unroll
        for (int i = 0; i < KK; ++i) {
            cw += vals[i] * invw;
            ch += vals[10 + i] * invh;
            const float xnext = fmaf(6.0f, cw, -BB);
            const float ynext = fmaf(6.0f, ch, -BB);
            const float dnext = (i == KK - 1) ? 1.0f : sp[i];
            const bool c = (i == 0) || (uc >= xprev);
            if (c) { xk = xprev; yk = yprev; wk = xnext - xprev; hk2 = ynext - yprev; dk = dprev; dk1 = dnext; }
            xprev = xnext; yprev = ynext; dprev = dnext;
        }

        const float sk = __fdividef(hk2, wk);
        const float xi = __fdividef(uc - xk, wk);
        const float om = 1.0f - xi;
        const float denom = sk + (dk1 + dk - 2.0f * sk) * xi * om;
        const float ynum = sk * xi * xi + dk * xi * om;
        const float yv = yk + hk2 * __fdividef(ynum, denom);
        const float larg = dk1 * xi * xi + 2.0f * sk * xi * om + dk * om * om;
        const float ldet = 2.0f * __logf(sk) + __logf(larg) - 2.0f * __logf(denom);

        out[g * 16 + 8 + d] = inside ? yv : ud;
        ldacc += inside ? ldet : 0.0f;
    }

    // ---- logdet: wave shuffle-reduce -> slot-spread atomics (64 slots) ----
    #pragma unroll
    for (int off = 32; off > 0; off >>= 1) ldacc += __shfl_down(ldacc, off);
    if (lane == 0) atomicAdd(&slots[blockIdx.x & 63], ldacc);
}

// ---- finish: sum the 64 partial slots into the scalar logdet output ----
__global__ void nsf_finish(const float* __restrict__ slots, float* __restrict__ ldp) {
    float v = slots[threadIdx.x];
    #pragma unroll
    for (int off = 32; off > 0; off >>= 1) v += __shfl_down(v, off);
    if (threadIdx.x == 0) *ldp = v;
}

extern "C" void kernel_launch(void* const* d_in, const int* in_sizes, int n_in,
                              void* d_out, int out_size, void* d_ws, size_t ws_size,
                              hipStream_t stream) {
    const float* x  = (const float*)d_in[0];
    const float* w0 = (const float*)d_in[1];
    const float* b0 = (const float*)d_in[2];
    const float* w1 = (const float*)d_in[3];
    const float* b1 = (const float*)d_in[4];
    const float* ww = (const float*)d_in[5];
    const float* bw = (const float*)d_in[6];
    const float* wh = (const float*)d_in[7];
    const float* bh = (const float*)d_in[8];
    const float* wd = (const float*)d_in[9];
    const float* bd = (const float*)d_in[10];

    float* out = (float*)d_out;
    float* ldp = out + (size_t)NROWS * 16;   // scalar logdet sum slot
    v8h* wsv = (v8h*)d_ws;                   // 45 KB packed B-fragments (bias folded)
    float* wsf = (float*)d_ws;               // f32 view for slots
    float* slots = wsf + SLOTS_OFF;

    hipLaunchKernelGGL(nsf_prep, dim3((FRAG_TOTAL + 255) / 256), dim3(256), 0, stream,
                       w0, b0, w1, b1, ww, bw, wh, bh, wd, bd, wsv, wsf);
    hipLaunchKernelGGL(nsf_main, dim3(NROWS / 32), dim3(64), 0, stream,
                       x, wsv, out, slots);
    hipLaunchKernelGGL(nsf_finish, dim3(1), dim3(64), 0, stream, slots, ldp);
}